// Round 15
// baseline (237.105 us; speedup 1.0000x reference)
//
#include <hip/hip_runtime.h>
#include <hip/hip_bf16.h>
#include <math.h>

#define DMODEL 1024
#define LSEQ   2048
#define BATCH  2
#define NHEADS 16
#define DHEAD  64
#define DFF    4096
#define MROWS  (BATCH*LSEQ)   // 4096

typedef __attribute__((ext_vector_type(8))) short short8;
typedef __attribute__((ext_vector_type(4))) float f32x4;
using bf16 = __hip_bfloat16;

static __device__ __forceinline__ f32x4 mfma16(short8 a, short8 b, f32x4 c) {
    return __builtin_amdgcn_mfma_f32_16x16x32_bf16(a, b, c, 0, 0, 0);
}

static __device__ __forceinline__ void gload16(const void* g, void* l) {
    __builtin_amdgcn_global_load_lds(
        (const __attribute__((address_space(1))) char*)g,
        (__attribute__((address_space(3))) char*)l, 16, 0, 0);
}

static __device__ __forceinline__ bf16 b16(float v) { return __float2bfloat16(v); }
static __device__ __forceinline__ float f32(bf16 v) { return __bfloat162float(v); }

// ---------------- all fp32 -> bf16 conversions + bias concat, ONE dispatch --------
__global__ void f2b_all(const float* __restrict__ x, const float* __restrict__ W1,
                        const float* __restrict__ W2,
                        const float* Wq, const float* Wk, const float* Wv, const float* Wo,
                        const float* bq, const float* bk, const float* bv,
                        bf16* __restrict__ xb, bf16* __restrict__ W1b, bf16* __restrict__ W2b,
                        bf16* __restrict__ Wqkvb, bf16* __restrict__ Wob,
                        float* __restrict__ bqkv) {
    int i = blockIdx.x * blockDim.x + threadIdx.x;
    const float* in; bf16* out;
    switch (blockIdx.y) {
        case 0: in = x;  out = xb;  break;
        case 1: in = W1; out = W1b; break;
        case 2: in = W2; out = W2b; break;
        case 3: {
            const int w = i >> 18, r = i & ((1 << 18) - 1);   // 256K float4 per weight
            const float* ws4[4] = {Wq, Wk, Wv, Wo};
            bf16* os4[4] = {Wqkvb, Wqkvb + (DMODEL * DMODEL), Wqkvb + 2 * (DMODEL * DMODEL), Wob};
            float4 v = reinterpret_cast<const float4*>(ws4[w])[r];
            union { ushort4 u; bf16 h[4]; } o;
            o.h[0] = b16(v.x); o.h[1] = b16(v.y); o.h[2] = b16(v.z); o.h[3] = b16(v.w);
            reinterpret_cast<ushort4*>(os4[w])[r] = o.u;
            return;
        }
        default:
            if (i < DMODEL / 4) {
                reinterpret_cast<float4*>(bqkv)[i]                  = reinterpret_cast<const float4*>(bq)[i];
                reinterpret_cast<float4*>(bqkv)[DMODEL / 4 + i]     = reinterpret_cast<const float4*>(bk)[i];
                reinterpret_cast<float4*>(bqkv)[2 * DMODEL / 4 + i] = reinterpret_cast<const float4*>(bv)[i];
            }
            return;
    }
    float4 v = reinterpret_cast<const float4*>(in)[i];
    union { ushort4 u; bf16 h[4]; } o;
    o.h[0] = b16(v.x); o.h[1] = b16(v.y); o.h[2] = b16(v.z); o.h[3] = b16(v.w);
    reinterpret_cast<ushort4*>(out)[i] = o.u;
}

// ------- split-K reduce: rr(bf16) = res + sum_s P_s(bf16) + bias -------------------
template<int S, bool RESB16>
__global__ __launch_bounds__(256) void reduce_kernel(const void* __restrict__ resv,
                                                     const bf16* __restrict__ P,
                                                     const float* __restrict__ bias,
                                                     bf16* __restrict__ outb, int n4) {
    int i = blockIdx.x * blockDim.x + threadIdx.x;
    if (i >= n4) return;
    float4 acc;
    if (RESB16) {
        union { ushort4 u; bf16 h[4]; } r;
        r.u = reinterpret_cast<const ushort4*>(resv)[i];
        acc.x = f32(r.h[0]); acc.y = f32(r.h[1]); acc.z = f32(r.h[2]); acc.w = f32(r.h[3]);
    } else {
        acc = reinterpret_cast<const float4*>(resv)[i];
    }
#pragma unroll
    for (int s = 0; s < S; ++s) {
        union { ushort4 u; bf16 h[4]; } p;
        p.u = reinterpret_cast<const ushort4*>(P)[i + (size_t)s * (MROWS * DMODEL / 4)];
        acc.x += f32(p.h[0]); acc.y += f32(p.h[1]);
        acc.z += f32(p.h[2]); acc.w += f32(p.h[3]);
    }
    float4 bs = reinterpret_cast<const float4*>(bias)[i & (DMODEL / 4 - 1)];
    union { ushort4 u; bf16 h[4]; } o;
    o.h[0] = b16(acc.x + bs.x); o.h[1] = b16(acc.y + bs.y);
    o.h[2] = b16(acc.z + bs.z); o.h[3] = b16(acc.w + bs.w);
    reinterpret_cast<ushort4*>(outb)[i] = o.u;
}

// ---------------- GEMM 256x128 tile, BK=32, ring-3, counted vmcnt(6) ----------
// 256 threads = 4 waves (2M x 2N), wave tile 128x64 (acc[8][4]).  72 KB LDS ->
// 2 blocks/CU co-residency + counted-vmcnt pipeline: stage kt+2 during iter kt,
// boundary waits vmcnt(6) (kt+1 landed, kt+2's 6 loads stay in flight — never
// drain to 0 mid-loop).  Hazard ledger: reads of buf[kt%3] protected by previous
// boundary vmcnt(6)+barrier; staging targets buf[(kt+2)%3] whose reads finished
// before the barrier the stage is issued after.  T2 swizzle = verified mapping.
// EPI: 0 fp32+bias, 1 GELU+bf16, 2 bf16+bias, 3 bf16 partial (blockIdx.z = k-slice)
template<int EPI>
__global__ __launch_bounds__(256, 2) void gemmT(const bf16* __restrict__ A,
                                                const bf16* __restrict__ W,
                                                const float* __restrict__ bias,
                                                void* __restrict__ Cout,
                                                int M, int N, int lda, int ldw,
                                                int K, int nn) {
    __shared__ bf16 sm[36864];   // 3 bufs x (A 16KB | B 8KB) = 72 KB
    const int t    = threadIdx.x;
    const int wave = t >> 6, lane = t & 63;
    const int lr   = lane & 15, lkb = lane >> 4;
    const int wm   = wave >> 1, wn = wave & 1;
    const int sk   = blockIdx.z;

    // XCD-aware bijective swizzle (all gridDim.x % 8 == 0)
    const int nwg = gridDim.x;
    const int bid = blockIdx.x;
    const int wg  = (bid & 7) * (nwg >> 3) + (bid >> 3);
    const int m0  = (wg / nn) * 256;
    const int n0  = (wg % nn) * 128;

    // staging: 6 gload16 per K-tile per thread (A:4 units, B:2 units)
    const bf16* src[6];
    int dbase[6];
#pragma unroll
    for (int u = 0; u < 6; ++u) {
        const int q  = (u < 4 ? u : u - 4) * 256 + t;   // 16B-slot index in region
        const int R  = q >> 3;                          // 128B super-row
        const int ss = (q & 7) ^ (R & 7);
        const int rp = ss >> 2, c = (ss & 3) * 8;
        if (u < 4) {
            src[u]   = A + (size_t)(m0 + 2 * R + rp) * lda + (size_t)sk * K + c;
            dbase[u] = u * 4096 + wave * 1024;          // wave-uniform; HW adds lane*16
        } else {
            src[u]   = W + (size_t)(n0 + 2 * R + rp) * ldw + (size_t)sk * K + c;
            dbase[u] = 16384 + (u - 4) * 4096 + wave * 1024;
        }
    }
    char* smb = (char*)sm;

    // ds_read byte offsets (XOR-swizzled; 2 lanes/bank = free)
    int aoff[8], boff[4];
#pragma unroll
    for (int i = 0; i < 8; ++i) {
        const int r = wm * 128 + i * 16 + lr, R = r >> 1;
        aoff[i] = R * 128 + ((((r & 1) << 2) | lkb) ^ (R & 7)) * 16;
    }
#pragma unroll
    for (int j = 0; j < 4; ++j) {
        const int r = wn * 64 + j * 16 + lr, R = r >> 1;
        boff[j] = 16384 + R * 128 + ((((r & 1) << 2) | lkb) ^ (R & 7)) * 16;
    }

    f32x4 acc[8][4];
#pragma unroll
    for (int i = 0; i < 8; ++i)
#pragma unroll
        for (int j = 0; j < 4; ++j)
            acc[i][j] = (f32x4){0.f, 0.f, 0.f, 0.f};

    const int nt = K >> 5;
    auto STAGE = [&](int bufoff, int kt) {
        const int koff = kt * 32;
#pragma unroll
        for (int u = 0; u < 6; ++u)
            gload16(src[u] + koff, smb + bufoff + dbase[u]);
    };

    // prologue: tile0 + tile1 in flight; wait only for tile0 (6 loads stay out)
    STAGE(0, 0);
    if (nt > 1) STAGE(24576, 1);
    __builtin_amdgcn_sched_barrier(0);
    if (nt > 1) asm volatile("s_waitcnt vmcnt(6)" ::: "memory");
    else        asm volatile("s_waitcnt vmcnt(0)" ::: "memory");
    __builtin_amdgcn_s_barrier();
    __builtin_amdgcn_sched_barrier(0);

    int curoff = 0, stgoff = 49152;
    for (int kt = 0; kt < nt; ++kt) {
        const bool pre = (kt + 2 < nt);
        if (pre) STAGE(stgoff, kt + 2);   // issue 2 tiles ahead
        short8 a[8], b[4];
#pragma unroll
        for (int i = 0; i < 8; ++i)
            a[i] = *reinterpret_cast<const short8*>(smb + curoff + aoff[i]);
#pragma unroll
        for (int j = 0; j < 4; ++j)
            b[j] = *reinterpret_cast<const short8*>(smb + curoff + boff[j]);
        __builtin_amdgcn_s_setprio(1);
#pragma unroll
        for (int i = 0; i < 8; ++i)
#pragma unroll
            for (int j = 0; j < 4; ++j)
                acc[i][j] = mfma16(b[j], a[i], acc[i][j]);   // swapped operands
        __builtin_amdgcn_s_setprio(0);
        if (kt + 1 < nt) {
            __builtin_amdgcn_sched_barrier(0);
            if (pre) asm volatile("s_waitcnt vmcnt(6)" ::: "memory"); // kt+1 landed, kt+2 in flight
            else     asm volatile("s_waitcnt vmcnt(0)" ::: "memory"); // tail drain
            __builtin_amdgcn_s_barrier();
            __builtin_amdgcn_sched_barrier(0);
        }
        if (pre) stgoff = (stgoff == 49152) ? 0 : stgoff + 24576;
        curoff = (curoff == 49152) ? 0 : curoff + 24576;
    }

    // epilogue: row = m0+wm*128+i*16+lr, cols = n0+wn*64+j*16+lkb*4 + 0..3
#pragma unroll
    for (int i = 0; i < 8; ++i) {
        const int row = m0 + wm * 128 + i * 16 + lr;
#pragma unroll
        for (int j = 0; j < 4; ++j) {
            const int col = n0 + wn * 64 + j * 16 + lkb * 4;
            f32x4 v = acc[i][j];
            if (EPI != 3) {
                float4 bs = *reinterpret_cast<const float4*>(&bias[col]);
                v[0] += bs.x; v[1] += bs.y; v[2] += bs.z; v[3] += bs.w;
            }
            if (EPI == 0) {
                float4 ov; ov.x = v[0]; ov.y = v[1]; ov.z = v[2]; ov.w = v[3];
                *reinterpret_cast<float4*>(&((float*)Cout)[(size_t)row * N + col]) = ov;
            } else if (EPI == 1) {
                union { ushort4 u; bf16 h[4]; } ob;
#pragma unroll
                for (int q = 0; q < 4; ++q) {
                    float x = v[q];
                    float u2 = x * (1.5957691216f + 0.0713548162f * x * x);
                    float e = __expf(fminf(u2, 60.f));
                    ob.h[q] = b16(x * (e / (e + 1.f)));   // x*sigmoid(2u) GELU
                }
                *reinterpret_cast<ushort4*>(
                    &reinterpret_cast<bf16*>(Cout)[(size_t)row * N + col]) = ob.u;
            } else if (EPI == 2) {
                union { ushort4 u; bf16 h[4]; } ob;
#pragma unroll
                for (int q = 0; q < 4; ++q) ob.h[q] = b16(v[q]);
                *reinterpret_cast<ushort4*>(
                    &reinterpret_cast<bf16*>(Cout)[(size_t)row * N + col]) = ob.u;
            } else {
                bf16* Pp = (bf16*)Cout + (size_t)sk * M * N;
                union { ushort4 u; bf16 h[4]; } ob;
#pragma unroll
                for (int q = 0; q < 4; ++q) ob.h[q] = b16(v[q]);
                *reinterpret_cast<ushort4*>(&Pp[(size_t)row * N + col]) = ob.u;
            }
        }
    }
}

// ---------------- fused attention (flash-style, bf16 MFMA, banded +-1 tile) -------
__global__ __launch_bounds__(256) void attn_kernel(const bf16* __restrict__ Q,
                                                   const bf16* __restrict__ Km,
                                                   const bf16* __restrict__ V,
                                                   bf16* __restrict__ O,
                                                   int ldq, int ldo) {
    __shared__ bf16 Qs[64][72];
    __shared__ bf16 Ks[64][72];
    __shared__ bf16 VsT[64][72];   // transposed V tile: VsT[d][m]
    __shared__ bf16 Ps[64][72];
    const int t    = threadIdx.x;
    const int wave = t >> 6, lane = t & 63;
    const int lr   = lane & 15, lkb = lane >> 4;
    const int qt   = blockIdx.x;
    const int q0   = qt * 64;
    const int b    = blockIdx.y >> 4, h = blockIdx.y & 15;
    const size_t base  = (size_t)b * LSEQ * ldq + (size_t)h * DHEAD;
    const size_t baseo = (size_t)b * LSEQ * ldo + (size_t)h * DHEAD;

#pragma unroll
    for (int p = 0; p < 2; ++p) {
        int idx = t + p * 256;
        int row = idx >> 3, c = (idx & 7) * 8;
        *reinterpret_cast<uint4*>(&Qs[row][c]) =
            *reinterpret_cast<const uint4*>(&Q[base + (size_t)(q0 + row) * ldq + c]);
    }
    __syncthreads();
    short8 qa[2];
    qa[0] = *reinterpret_cast<const short8*>(&Qs[wave * 16 + lr][lkb * 8]);
    qa[1] = *reinterpret_cast<const short8*>(&Qs[wave * 16 + lr][32 + lkb * 8]);

    f32x4 o[4];
#pragma unroll
    for (int dj = 0; dj < 4; ++dj) o[dj] = (f32x4){0.f, 0.f, 0.f, 0.f};
    float mrun[4], lrun[4];
#pragma unroll
    for (int q = 0; q < 4; ++q) { mrun[q] = -1e30f; lrun[q] = 0.f; }

    int kt0 = qt - 1; if (kt0 < 0) kt0 = 0;
    int kt1 = qt + 1; if (kt1 > LSEQ / 64 - 1) kt1 = LSEQ / 64 - 1;

    for (int kt = kt0; kt <= kt1; ++kt) {
        const int k0 = kt * 64;
        __syncthreads();
#pragma unroll
        for (int p = 0; p < 2; ++p) {
            int idx = t + p * 256;
            int row = idx >> 3, c = (idx & 7) * 8;
            *reinterpret_cast<uint4*>(&Ks[row][c]) =
                *reinterpret_cast<const uint4*>(&Km[base + (size_t)(k0 + row) * ldq + c]);
        }
        {
            const int vl = lane, vw = wave;
#pragma unroll
            for (int p = 0; p < 2; ++p) {
                int c = vw * 8 + p * 32;
                union { uint4 u; bf16 hh[8]; } tv;
                tv.u = *reinterpret_cast<const uint4*>(&V[base + (size_t)(k0 + vl) * ldq + c]);
#pragma unroll
                for (int e = 0; e < 8; ++e) VsT[c + e][vl] = tv.hh[e];
            }
        }
        __syncthreads();

        f32x4 s[4];
#pragma unroll
        for (int j = 0; j < 4; ++j) {
            short8 kb0 = *reinterpret_cast<const short8*>(&Ks[j * 16 + lr][lkb * 8]);
            short8 kb1 = *reinterpret_cast<const short8*>(&Ks[j * 16 + lr][32 + lkb * 8]);
            f32x4 z = (f32x4){0.f, 0.f, 0.f, 0.f};
            z = mfma16(qa[0], kb0, z);
            z = mfma16(qa[1], kb1, z);
            s[j] = z;
        }
        float mx[4];
#pragma unroll
        for (int q = 0; q < 4; ++q) mx[q] = -1e30f;
#pragma unroll
        for (int j = 0; j < 4; ++j) {
            int cm = k0 + j * 16 + lr;
#pragma unroll
            for (int q = 0; q < 4; ++q) {
                int rq = q0 + wave * 16 + lkb * 4 + q;
                float sv = s[j][q] * 0.125f - 0.1f * fabsf((float)(rq - cm));
                s[j][q] = sv;
                mx[q] = fmaxf(mx[q], sv);
            }
        }
#pragma unroll
        for (int q = 0; q < 4; ++q) {
#pragma unroll
            for (int off = 1; off < 16; off <<= 1)
                mx[q] = fmaxf(mx[q], __shfl_xor(mx[q], off));
        }
        float alpha[4];
#pragma unroll
        for (int q = 0; q < 4; ++q) {
            float mnew = fmaxf(mrun[q], mx[q]);
            alpha[q] = __expf(mrun[q] - mnew);
            mrun[q] = mnew;
        }
        float rs[4] = {0.f, 0.f, 0.f, 0.f};
#pragma unroll
        for (int j = 0; j < 4; ++j) {
#pragma unroll
            for (int q = 0; q < 4; ++q) {
                float p = __expf(s[j][q] - mrun[q]);
                rs[q] += p;
                Ps[wave * 16 + lkb * 4 + q][j * 16 + lr] = b16(p);
            }
        }
#pragma unroll
        for (int q = 0; q < 4; ++q) {
#pragma unroll
            for (int off = 1; off < 16; off <<= 1)
                rs[q] += __shfl_xor(rs[q], off);
            lrun[q] = lrun[q] * alpha[q] + rs[q];
        }
#pragma unroll
        for (int dj = 0; dj < 4; ++dj)
#pragma unroll
            for (int q = 0; q < 4; ++q) o[dj][q] *= alpha[q];
        // no barrier: Ps rows are wave-private

        short8 pa0 = *reinterpret_cast<const short8*>(&Ps[wave * 16 + lr][lkb * 8]);
        short8 pa1 = *reinterpret_cast<const short8*>(&Ps[wave * 16 + lr][32 + lkb * 8]);
#pragma unroll
        for (int dj = 0; dj < 4; ++dj) {
            short8 vb0 = *reinterpret_cast<const short8*>(&VsT[dj * 16 + lr][lkb * 8]);
            short8 vb1 = *reinterpret_cast<const short8*>(&VsT[dj * 16 + lr][32 + lkb * 8]);
            o[dj] = mfma16(pa0, vb0, o[dj]);
            o[dj] = mfma16(pa1, vb1, o[dj]);
        }
    }

#pragma unroll
    for (int dj = 0; dj < 4; ++dj) {
#pragma unroll
        for (int q = 0; q < 4; ++q) {
            int row = q0 + wave * 16 + lkb * 4 + q;
            int col = dj * 16 + lr;
            float val = o[dj][q] / lrun[q];
            O[baseo + (size_t)row * ldo + col] = b16(val);
        }
    }
}

// ------- moving average (k=25) + LayerNorm, 4 rows/block, XCD-chunked, bf16 in -----
__global__ __launch_bounds__(256) void mavg_ln4_kernel(const bf16* __restrict__ r,
                                                       const float* __restrict__ g,
                                                       const float* __restrict__ be,
                                                       float* __restrict__ out,
                                                       bf16* __restrict__ outb) {
    const int gid = (blockIdx.x & 7) * (MROWS / 8 / 4) + (blockIdx.x >> 3); // bijective
    const int row0 = gid * 4;
    const int b = row0 >> 11, l0 = row0 & 2047;
    const int t = threadIdx.x, c = t * 4;
    const bf16* base = r + (size_t)b * LSEQ * DMODEL;

    float4 s[4];
#pragma unroll
    for (int o = 0; o < 4; ++o) s[o] = (float4){0.f, 0.f, 0.f, 0.f};
    int j0 = l0 - 12; if (j0 < 0) j0 = 0;
    int j1 = l0 + 15; if (j1 > LSEQ - 1) j1 = LSEQ - 1;
    for (int j = j0; j <= j1; ++j) {
        union { ushort4 u; bf16 h[4]; } rv;
        rv.u = *reinterpret_cast<const ushort4*>(&base[(size_t)j * DMODEL + c]);
        float4 v; v.x = f32(rv.h[0]); v.y = f32(rv.h[1]); v.z = f32(rv.h[2]); v.w = f32(rv.h[3]);
#pragma unroll
        for (int o = 0; o < 4; ++o) {
            const int lo = l0 + o;
            if (j >= lo - 12 && j <= lo + 12) {
                s[o].x += v.x; s[o].y += v.y; s[o].z += v.z; s[o].w += v.w;
            }
        }
    }
    const float kinv = 1.0f / 25.0f;
    float4 tr[4];
    float p1[4], p2[4];
#pragma unroll
    for (int o = 0; o < 4; ++o) {
        tr[o].x = s[o].x * kinv; tr[o].y = s[o].y * kinv;
        tr[o].z = s[o].z * kinv; tr[o].w = s[o].w * kinv;
        p1[o] = tr[o].x + tr[o].y + tr[o].z + tr[o].w;
        p2[o] = tr[o].x * tr[o].x + tr[o].y * tr[o].y + tr[o].z * tr[o].z + tr[o].w * tr[o].w;
    }
    const int lane = t & 63, wv = t >> 6;
#pragma unroll
    for (int off = 1; off < 64; off <<= 1) {
#pragma unroll
        for (int o = 0; o < 4; ++o) {
            p1[o] += __shfl_xor(p1[o], off);
            p2[o] += __shfl_xor(p2[o], off);
        }
    }
    __shared__ float red[4][8];
    if (lane == 0) {
#pragma unroll
        for (int o = 0; o < 4; ++o) { red[wv][o] = p1[o]; red[wv][4 + o] = p2[o]; }
    }
    __syncthreads();
    float4 gg = *reinterpret_cast<const float4*>(&g[c]);
    float4 bb = *reinterpret_cast<const float4*>(&be[c]);
#pragma unroll
    for (int o = 0; o < 4; ++o) {
        float q1 = red[0][o] + red[1][o] + red[2][o] + red[3][o];
        float q2 = red[0][4 + o] + red[1][4 + o] + red[2][4 + o] + red[3][4 + o];
        const float mu  = q1 * (1.0f / 1024.0f);
        const float var = q2 * (1.0f / 1024.0f) - mu * mu;
        const float inv = rsqrtf(var + 1e-5f);
        float o0 = (tr[o].x - mu) * inv * gg.x + bb.x;
        float o1 = (tr[o].y - mu) * inv * gg.y + bb.y;
        float o2 = (tr[o].z - mu) * inv * gg.z + bb.z;
        float o3 = (tr[o].w - mu) * inv * gg.w + bb.w;
        if (out) {
            float4 ov; ov.x = o0; ov.y = o1; ov.z = o2; ov.w = o3;
            *reinterpret_cast<float4*>(&out[(size_t)(row0 + o) * DMODEL + c]) = ov;
        }
        if (outb) {
            union { ushort4 u; bf16 hh[4]; } ob;
            ob.hh[0] = b16(o0); ob.hh[1] = b16(o1); ob.hh[2] = b16(o2); ob.hh[3] = b16(o3);
            reinterpret_cast<ushort4*>(outb + (size_t)(row0 + o) * DMODEL)[t] = ob.u;
        }
    }
}

extern "C" void kernel_launch(void* const* d_in, const int* in_sizes, int n_in,
                              void* d_out, int out_size, void* d_ws, size_t ws_size,
                              hipStream_t stream) {
    const float* x   = (const float*)d_in[0];
    const float* Wq  = (const float*)d_in[1];
    const float* bq  = (const float*)d_in[2];
    const float* Wk  = (const float*)d_in[3];
    const float* bk  = (const float*)d_in[4];
    const float* Wv  = (const float*)d_in[5];
    const float* bv  = (const float*)d_in[6];
    const float* Wo  = (const float*)d_in[7];
    const float* bo  = (const float*)d_in[8];
    const float* W1  = (const float*)d_in[9];
    const float* b1  = (const float*)d_in[10];
    const float* W2  = (const float*)d_in[11];
    const float* b2  = (const float*)d_in[12];
    const float* g1  = (const float*)d_in[13];
    const float* be1 = (const float*)d_in[14];
    const float* g2  = (const float*)d_in[15];
    const float* be2 = (const float*)d_in[16];
    float* out = (float*)d_out;
    char* ws = (char*)d_ws;
    const size_t MB = 1u << 20;

    // timeline-overlapped layout (152MB total):
    bf16* xb    = (bf16*)(ws + 0);         //  8MB  (1-2)
    bf16* rrb   = (bf16*)(ws + 8 * MB);    //  8MB  (5-6, 9-10)
    bf16* qkvb  = (bf16*)(ws + 16 * MB);   // 24MB  (2-3)
    bf16* ab    = (bf16*)(ws + 16 * MB);   //  8MB  (6-9; qkvb dead after attn)
    bf16* hb    = (bf16*)(ws + 24 * MB);   // 32MB  (7-8)
    bf16* aob   = (bf16*)(ws + 40 * MB);   //  8MB  (3-4)
    bf16* Wqkvb = (bf16*)(ws + 48 * MB);   //  6MB  (1-2)
    bf16* Wob   = (bf16*)(ws + 54 * MB);   //  2MB  (1-4)
    bf16* W1b   = (bf16*)(ws + 56 * MB);   //  8MB  (1-7)
    bf16* W2b   = (bf16*)(ws + 64 * MB);   //  8MB  (1-8)
    bf16* P     = (bf16*)(ws + 72 * MB);   // 32MB  bf16 partials (4 slices x 8MB)
    float* bqkv = (float*)(ws + 136 * MB); // 12KB  (1-2)

    // 1. all conversions + bias concat (one dispatch)
    f2b_all<<<dim3((MROWS * DMODEL / 4) / 256, 5), 256, 0, stream>>>(
        x, W1, W2, Wq, Wk, Wv, Wo, bq, bk, bv,
        xb, W1b, W2b, Wqkvb, Wob, bqkv);

    // 2. fused QKV projection -> qkvb [4096][3072]  (16x24 = 384 blocks)
    gemmT<2><<<dim3(384, 1, 1), 256, 0, stream>>>(xb, Wqkvb, bqkv, qkvb,
                                                  MROWS, 3 * DMODEL, DMODEL, DMODEL, DMODEL, 24);
    // 3. attention (banded +-1 tile)
    attn_kernel<<<dim3(32, 32), 256, 0, stream>>>(qkvb, qkvb + DMODEL, qkvb + 2 * DMODEL,
                                                  aob, 3 * DMODEL, DMODEL);
    // 4. output projection, split-K=2 -> P[0:2] (bf16)  (16x8 x2 = 256 blocks)
    gemmT<3><<<dim3(128, 1, 2), 256, 0, stream>>>(aob, Wob, nullptr, P,
                                                  MROWS, DMODEL, DMODEL, DMODEL, DMODEL / 2, 8);
    // 5. rrb = x + sum(P0,P1) + bo  (bf16 out)
    reduce_kernel<2, false><<<(MROWS * DMODEL / 4) / 256, 256, 0, stream>>>(
        x, P, bo, rrb, MROWS * DMODEL / 4);
    // 6. movavg + LN1 -> ab (bf16 only)
    mavg_ln4_kernel<<<MROWS / 4, 256, 0, stream>>>(rrb, g1, be1, nullptr, ab);
    // 7. FF1 (GELU, bf16 out)  (16x32 = 512 blocks)
    gemmT<1><<<dim3(512, 1, 1), 256, 0, stream>>>(ab, W1b, b1, hb,
                                                  MROWS, DFF, DMODEL, DMODEL, DMODEL, 32);
    // 8. FF2, split-K=4 -> P[0:4] (bf16)  (16x8 x4 = 512 blocks)
    gemmT<3><<<dim3(128, 1, 4), 256, 0, stream>>>(hb, W2b, nullptr, P,
                                                  MROWS, DMODEL, DFF, DFF, DFF / 4, 8);
    // 9. rrb = ab + sum(P0..P3) + b2  (bf16 residual in, bf16 out)
    reduce_kernel<4, true><<<(MROWS * DMODEL / 4) / 256, 256, 0, stream>>>(
        ab, P, b2, rrb, MROWS * DMODEL / 4);
    // 10. movavg + LN2 -> out (fp32)
    mavg_ln4_kernel<<<MROWS / 4, 256, 0, stream>>>(rrb, g2, be2, out, nullptr);
}

// Round 16
// 235.488 us; speedup vs baseline: 1.0069x; 1.0069x over previous
//
#include <hip/hip_runtime.h>
#include <hip/hip_bf16.h>
#include <math.h>

#define DMODEL 1024
#define LSEQ   2048
#define BATCH  2
#define NHEADS 16
#define DHEAD  64
#define DFF    4096
#define MROWS  (BATCH*LSEQ)   // 4096

typedef __attribute__((ext_vector_type(8))) short short8;
typedef __attribute__((ext_vector_type(4))) float f32x4;
using bf16 = __hip_bfloat16;

static __device__ __forceinline__ f32x4 mfma16(short8 a, short8 b, f32x4 c) {
    return __builtin_amdgcn_mfma_f32_16x16x32_bf16(a, b, c, 0, 0, 0);
}

static __device__ __forceinline__ void gload16(const void* g, void* l) {
    __builtin_amdgcn_global_load_lds(
        (const __attribute__((address_space(1))) char*)g,
        (__attribute__((address_space(3))) char*)l, 16, 0, 0);
}

static __device__ __forceinline__ bf16 b16(float v) { return __float2bfloat16(v); }
static __device__ __forceinline__ float f32(bf16 v) { return __bfloat162float(v); }

// ---------------- all fp32 -> bf16 conversions + bias concat, ONE dispatch --------
// grid (4096, 4): y=0 x (+bias concat in first 256 lanes of block 0), y=1 W1,
// y=2 W2, y=3 Wq|Wk|Wv|Wo (4 x 256K float4 selected by i>>18).
__global__ void f2b_all(const float* __restrict__ x, const float* __restrict__ W1,
                        const float* __restrict__ W2,
                        const float* Wq, const float* Wk, const float* Wv, const float* Wo,
                        const float* bq, const float* bk, const float* bv,
                        bf16* __restrict__ xb, bf16* __restrict__ W1b, bf16* __restrict__ W2b,
                        bf16* __restrict__ Wqkvb, bf16* __restrict__ Wob,
                        float* __restrict__ bqkv) {
    int i = blockIdx.x * blockDim.x + threadIdx.x;
    const float* in; bf16* out;
    switch (blockIdx.y) {
        case 0:
            in = x; out = xb;
            if (i < DMODEL / 4) {   // fold bias concat into the x-conversion slice
                reinterpret_cast<float4*>(bqkv)[i]                  = reinterpret_cast<const float4*>(bq)[i];
                reinterpret_cast<float4*>(bqkv)[DMODEL / 4 + i]     = reinterpret_cast<const float4*>(bk)[i];
                reinterpret_cast<float4*>(bqkv)[2 * DMODEL / 4 + i] = reinterpret_cast<const float4*>(bv)[i];
            }
            break;
        case 1: in = W1; out = W1b; break;
        case 2: in = W2; out = W2b; break;
        default: {
            const int w = i >> 18, r = i & ((1 << 18) - 1);   // 256K float4 per weight
            const float* ws4[4] = {Wq, Wk, Wv, Wo};
            bf16* os4[4] = {Wqkvb, Wqkvb + (DMODEL * DMODEL), Wqkvb + 2 * (DMODEL * DMODEL), Wob};
            float4 v = reinterpret_cast<const float4*>(ws4[w])[r];
            union { ushort4 u; bf16 h[4]; } o;
            o.h[0] = b16(v.x); o.h[1] = b16(v.y); o.h[2] = b16(v.z); o.h[3] = b16(v.w);
            reinterpret_cast<ushort4*>(os4[w])[r] = o.u;
            return;
        }
    }
    float4 v = reinterpret_cast<const float4*>(in)[i];
    union { ushort4 u; bf16 h[4]; } o;
    o.h[0] = b16(v.x); o.h[1] = b16(v.y); o.h[2] = b16(v.z); o.h[3] = b16(v.w);
    reinterpret_cast<ushort4*>(out)[i] = o.u;
}

// ------- split-K reduce: rr(bf16) = res + sum_s P_s(bf16) + bias -------------------
template<int S, bool RESB16>
__global__ __launch_bounds__(256) void reduce_kernel(const void* __restrict__ resv,
                                                     const bf16* __restrict__ P,
                                                     const float* __restrict__ bias,
                                                     bf16* __restrict__ outb, int n4) {
    int i = blockIdx.x * blockDim.x + threadIdx.x;
    if (i >= n4) return;
    float4 acc;
    if (RESB16) {
        union { ushort4 u; bf16 h[4]; } r;
        r.u = reinterpret_cast<const ushort4*>(resv)[i];
        acc.x = f32(r.h[0]); acc.y = f32(r.h[1]); acc.z = f32(r.h[2]); acc.w = f32(r.h[3]);
    } else {
        acc = reinterpret_cast<const float4*>(resv)[i];
    }
#pragma unroll
    for (int s = 0; s < S; ++s) {
        union { ushort4 u; bf16 h[4]; } p;
        p.u = reinterpret_cast<const ushort4*>(P)[i + (size_t)s * (MROWS * DMODEL / 4)];
        acc.x += f32(p.h[0]); acc.y += f32(p.h[1]);
        acc.z += f32(p.h[2]); acc.w += f32(p.h[3]);
    }
    float4 bs = reinterpret_cast<const float4*>(bias)[i & (DMODEL / 4 - 1)];
    union { ushort4 u; bf16 h[4]; } o;
    o.h[0] = b16(acc.x + bs.x); o.h[1] = b16(acc.y + bs.y);
    o.h[2] = b16(acc.z + bs.z); o.h[3] = b16(acc.w + bs.w);
    reinterpret_cast<ushort4*>(outb)[i] = o.u;
}

// ---------------- GEMM 256x128 tile, BK=32, ring-2, co-residency (R14 best) --------
// 256 threads = 4 waves (2M x 2N), wave tile 128x64 (acc[8][4]).  48 KB LDS ->
// 2-3 blocks/CU; co-resident blocks fill barrier/latency bubbles (m97/m114).
// EPI: 0 fp32+bias, 1 GELU+bf16, 2 bf16+bias, 3 bf16 partial (blockIdx.z = k-slice)
template<int EPI>
__global__ __launch_bounds__(256, 2) void gemmT(const bf16* __restrict__ A,
                                                const bf16* __restrict__ W,
                                                const float* __restrict__ bias,
                                                void* __restrict__ Cout,
                                                int M, int N, int lda, int ldw,
                                                int K, int nn) {
    __shared__ bf16 sm[24576];   // 2 bufs x (A 16KB | B 8KB) = 48 KB
    const int t    = threadIdx.x;
    const int wave = t >> 6, lane = t & 63;
    const int lr   = lane & 15, lkb = lane >> 4;
    const int wm   = wave >> 1, wn = wave & 1;
    const int sk   = blockIdx.z;

    // XCD-aware bijective swizzle (all gridDim.x % 8 == 0)
    const int nwg = gridDim.x;
    const int bid = blockIdx.x;
    const int wg  = (bid & 7) * (nwg >> 3) + (bid >> 3);
    const int m0  = (wg / nn) * 256;
    const int n0  = (wg % nn) * 128;

    // staging: 6 gload16 per K-tile per thread (A:4 units, B:2 units)
    const bf16* src[6];
    int dbase[6];
#pragma unroll
    for (int u = 0; u < 6; ++u) {
        const int q  = (u < 4 ? u : u - 4) * 256 + t;   // 16B-slot index in region
        const int R  = q >> 3;                          // 128B super-row
        const int ss = (q & 7) ^ (R & 7);
        const int rp = ss >> 2, c = (ss & 3) * 8;
        if (u < 4) {
            src[u]   = A + (size_t)(m0 + 2 * R + rp) * lda + (size_t)sk * K + c;
            dbase[u] = u * 4096 + wave * 1024;          // wave-uniform; HW adds lane*16
        } else {
            src[u]   = W + (size_t)(n0 + 2 * R + rp) * ldw + (size_t)sk * K + c;
            dbase[u] = 16384 + (u - 4) * 4096 + wave * 1024;
        }
    }
    char* smb = (char*)sm;

    // ds_read byte offsets (XOR-swizzled; 2 lanes/bank = free)
    int aoff[8], boff[4];
#pragma unroll
    for (int i = 0; i < 8; ++i) {
        const int r = wm * 128 + i * 16 + lr, R = r >> 1;
        aoff[i] = R * 128 + ((((r & 1) << 2) | lkb) ^ (R & 7)) * 16;
    }
#pragma unroll
    for (int j = 0; j < 4; ++j) {
        const int r = wn * 64 + j * 16 + lr, R = r >> 1;
        boff[j] = 16384 + R * 128 + ((((r & 1) << 2) | lkb) ^ (R & 7)) * 16;
    }

    f32x4 acc[8][4];
#pragma unroll
    for (int i = 0; i < 8; ++i)
#pragma unroll
        for (int j = 0; j < 4; ++j)
            acc[i][j] = (f32x4){0.f, 0.f, 0.f, 0.f};

    const int nt = K >> 5;
    auto STAGE = [&](int bufoff, int kt) {
        const int koff = kt * 32;
#pragma unroll
        for (int u = 0; u < 6; ++u)
            gload16(src[u] + koff, smb + bufoff + dbase[u]);
    };

    // prologue: tile0 only; drain and go
    STAGE(0, 0);
    __builtin_amdgcn_sched_barrier(0);
    asm volatile("s_waitcnt vmcnt(0)" ::: "memory");
    __builtin_amdgcn_s_barrier();
    __builtin_amdgcn_sched_barrier(0);

    int cur = 0;
    for (int kt = 0; kt < nt; ++kt) {
        if (kt + 1 < nt) STAGE((cur ^ 1) * 24576, kt + 1);   // issue early, land late
        short8 a[8], b[4];
#pragma unroll
        for (int i = 0; i < 8; ++i)
            a[i] = *reinterpret_cast<const short8*>(smb + cur * 24576 + aoff[i]);
#pragma unroll
        for (int j = 0; j < 4; ++j)
            b[j] = *reinterpret_cast<const short8*>(smb + cur * 24576 + boff[j]);
        __builtin_amdgcn_s_setprio(1);
#pragma unroll
        for (int i = 0; i < 8; ++i)
#pragma unroll
            for (int j = 0; j < 4; ++j)
                acc[i][j] = mfma16(b[j], a[i], acc[i][j]);   // swapped operands
        __builtin_amdgcn_s_setprio(0);
        __builtin_amdgcn_sched_barrier(0);
        asm volatile("s_waitcnt vmcnt(0)" ::: "memory");     // next tile landed
        __builtin_amdgcn_s_barrier();
        __builtin_amdgcn_sched_barrier(0);
        cur ^= 1;
    }

    // epilogue: row = m0+wm*128+i*16+lr, cols = n0+wn*64+j*16+lkb*4 + 0..3
#pragma unroll
    for (int i = 0; i < 8; ++i) {
        const int row = m0 + wm * 128 + i * 16 + lr;
#pragma unroll
        for (int j = 0; j < 4; ++j) {
            const int col = n0 + wn * 64 + j * 16 + lkb * 4;
            f32x4 v = acc[i][j];
            if (EPI != 3) {
                float4 bs = *reinterpret_cast<const float4*>(&bias[col]);
                v[0] += bs.x; v[1] += bs.y; v[2] += bs.z; v[3] += bs.w;
            }
            if (EPI == 0) {
                float4 ov; ov.x = v[0]; ov.y = v[1]; ov.z = v[2]; ov.w = v[3];
                *reinterpret_cast<float4*>(&((float*)Cout)[(size_t)row * N + col]) = ov;
            } else if (EPI == 1) {
                union { ushort4 u; bf16 h[4]; } ob;
#pragma unroll
                for (int q = 0; q < 4; ++q) {
                    float x = v[q];
                    float u2 = x * (1.5957691216f + 0.0713548162f * x * x);
                    float e = __expf(fminf(u2, 60.f));
                    ob.h[q] = b16(x * (e / (e + 1.f)));   // x*sigmoid(2u) GELU
                }
                *reinterpret_cast<ushort4*>(
                    &reinterpret_cast<bf16*>(Cout)[(size_t)row * N + col]) = ob.u;
            } else if (EPI == 2) {
                union { ushort4 u; bf16 h[4]; } ob;
#pragma unroll
                for (int q = 0; q < 4; ++q) ob.h[q] = b16(v[q]);
                *reinterpret_cast<ushort4*>(
                    &reinterpret_cast<bf16*>(Cout)[(size_t)row * N + col]) = ob.u;
            } else {
                bf16* Pp = (bf16*)Cout + (size_t)sk * M * N;
                union { ushort4 u; bf16 h[4]; } ob;
#pragma unroll
                for (int q = 0; q < 4; ++q) ob.h[q] = b16(v[q]);
                *reinterpret_cast<ushort4*>(&Pp[(size_t)row * N + col]) = ob.u;
            }
        }
    }
}

// ---------------- fused attention (flash-style, bf16 MFMA, banded +-1 tile) -------
__global__ __launch_bounds__(256) void attn_kernel(const bf16* __restrict__ Q,
                                                   const bf16* __restrict__ Km,
                                                   const bf16* __restrict__ V,
                                                   bf16* __restrict__ O,
                                                   int ldq, int ldo) {
    __shared__ bf16 Qs[64][72];
    __shared__ bf16 Ks[64][72];
    __shared__ bf16 VsT[64][72];   // transposed V tile: VsT[d][m]
    __shared__ bf16 Ps[64][72];
    const int t    = threadIdx.x;
    const int wave = t >> 6, lane = t & 63;
    const int lr   = lane & 15, lkb = lane >> 4;
    const int qt   = blockIdx.x;
    const int q0   = qt * 64;
    const int b    = blockIdx.y >> 4, h = blockIdx.y & 15;
    const size_t base  = (size_t)b * LSEQ * ldq + (size_t)h * DHEAD;
    const size_t baseo = (size_t)b * LSEQ * ldo + (size_t)h * DHEAD;

#pragma unroll
    for (int p = 0; p < 2; ++p) {
        int idx = t + p * 256;
        int row = idx >> 3, c = (idx & 7) * 8;
        *reinterpret_cast<uint4*>(&Qs[row][c]) =
            *reinterpret_cast<const uint4*>(&Q[base + (size_t)(q0 + row) * ldq + c]);
    }
    __syncthreads();
    short8 qa[2];
    qa[0] = *reinterpret_cast<const short8*>(&Qs[wave * 16 + lr][lkb * 8]);
    qa[1] = *reinterpret_cast<const short8*>(&Qs[wave * 16 + lr][32 + lkb * 8]);

    f32x4 o[4];
#pragma unroll
    for (int dj = 0; dj < 4; ++dj) o[dj] = (f32x4){0.f, 0.f, 0.f, 0.f};
    float mrun[4], lrun[4];
#pragma unroll
    for (int q = 0; q < 4; ++q) { mrun[q] = -1e30f; lrun[q] = 0.f; }

    int kt0 = qt - 1; if (kt0 < 0) kt0 = 0;
    int kt1 = qt + 1; if (kt1 > LSEQ / 64 - 1) kt1 = LSEQ / 64 - 1;

    for (int kt = kt0; kt <= kt1; ++kt) {
        const int k0 = kt * 64;
        __syncthreads();
#pragma unroll
        for (int p = 0; p < 2; ++p) {
            int idx = t + p * 256;
            int row = idx >> 3, c = (idx & 7) * 8;
            *reinterpret_cast<uint4*>(&Ks[row][c]) =
                *reinterpret_cast<const uint4*>(&Km[base + (size_t)(k0 + row) * ldq + c]);
        }
        {
            const int vl = lane, vw = wave;
#pragma unroll
            for (int p = 0; p < 2; ++p) {
                int c = vw * 8 + p * 32;
                union { uint4 u; bf16 hh[8]; } tv;
                tv.u = *reinterpret_cast<const uint4*>(&V[base + (size_t)(k0 + vl) * ldq + c]);
#pragma unroll
                for (int e = 0; e < 8; ++e) VsT[c + e][vl] = tv.hh[e];
            }
        }
        __syncthreads();

        f32x4 s[4];
#pragma unroll
        for (int j = 0; j < 4; ++j) {
            short8 kb0 = *reinterpret_cast<const short8*>(&Ks[j * 16 + lr][lkb * 8]);
            short8 kb1 = *reinterpret_cast<const short8*>(&Ks[j * 16 + lr][32 + lkb * 8]);
            f32x4 z = (f32x4){0.f, 0.f, 0.f, 0.f};
            z = mfma16(qa[0], kb0, z);
            z = mfma16(qa[1], kb1, z);
            s[j] = z;
        }
        float mx[4];
#pragma unroll
        for (int q = 0; q < 4; ++q) mx[q] = -1e30f;
#pragma unroll
        for (int j = 0; j < 4; ++j) {
            int cm = k0 + j * 16 + lr;
#pragma unroll
            for (int q = 0; q < 4; ++q) {
                int rq = q0 + wave * 16 + lkb * 4 + q;
                float sv = s[j][q] * 0.125f - 0.1f * fabsf((float)(rq - cm));
                s[j][q] = sv;
                mx[q] = fmaxf(mx[q], sv);
            }
        }
#pragma unroll
        for (int q = 0; q < 4; ++q) {
#pragma unroll
            for (int off = 1; off < 16; off <<= 1)
                mx[q] = fmaxf(mx[q], __shfl_xor(mx[q], off));
        }
        float alpha[4];
#pragma unroll
        for (int q = 0; q < 4; ++q) {
            float mnew = fmaxf(mrun[q], mx[q]);
            alpha[q] = __expf(mrun[q] - mnew);
            mrun[q] = mnew;
        }
        float rs[4] = {0.f, 0.f, 0.f, 0.f};
#pragma unroll
        for (int j = 0; j < 4; ++j) {
#pragma unroll
            for (int q = 0; q < 4; ++q) {
                float p = __expf(s[j][q] - mrun[q]);
                rs[q] += p;
                Ps[wave * 16 + lkb * 4 + q][j * 16 + lr] = b16(p);
            }
        }
#pragma unroll
        for (int q = 0; q < 4; ++q) {
#pragma unroll
            for (int off = 1; off < 16; off <<= 1)
                rs[q] += __shfl_xor(rs[q], off);
            lrun[q] = lrun[q] * alpha[q] + rs[q];
        }
#pragma unroll
        for (int dj = 0; dj < 4; ++dj)
#pragma unroll
            for (int q = 0; q < 4; ++q) o[dj][q] *= alpha[q];
        // no barrier: Ps rows are wave-private

        short8 pa0 = *reinterpret_cast<const short8*>(&Ps[wave * 16 + lr][lkb * 8]);
        short8 pa1 = *reinterpret_cast<const short8*>(&Ps[wave * 16 + lr][32 + lkb * 8]);
#pragma unroll
        for (int dj = 0; dj < 4; ++dj) {
            short8 vb0 = *reinterpret_cast<const short8*>(&VsT[dj * 16 + lr][lkb * 8]);
            short8 vb1 = *reinterpret_cast<const short8*>(&VsT[dj * 16 + lr][32 + lkb * 8]);
            o[dj] = mfma16(pa0, vb0, o[dj]);
            o[dj] = mfma16(pa1, vb1, o[dj]);
        }
    }

#pragma unroll
    for (int dj = 0; dj < 4; ++dj) {
#pragma unroll
        for (int q = 0; q < 4; ++q) {
            int row = q0 + wave * 16 + lkb * 4 + q;
            int col = dj * 16 + lr;
            float val = o[dj][q] / lrun[q];
            O[baseo + (size_t)row * ldo + col] = b16(val);
        }
    }
}

// ------- moving average (k=25) + LayerNorm, 4 rows/block, XCD-chunked, bf16 in -----
__global__ __launch_bounds__(256) void mavg_ln4_kernel(const bf16* __restrict__ r,
                                                       const float* __restrict__ g,
                                                       const float* __restrict__ be,
                                                       float* __restrict__ out,
                                                       bf16* __restrict__ outb) {
    const int gid = (blockIdx.x & 7) * (MROWS / 8 / 4) + (blockIdx.x >> 3); // bijective
    const int row0 = gid * 4;
    const int b = row0 >> 11, l0 = row0 & 2047;
    const int t = threadIdx.x, c = t * 4;
    const bf16* base = r + (size_t)b * LSEQ * DMODEL;

    float4 s[4];
#pragma unroll
    for (int o = 0; o < 4; ++o) s[o] = (float4){0.f, 0.f, 0.f, 0.f};
    int j0 = l0 - 12; if (j0 < 0) j0 = 0;
    int j1 = l0 + 15; if (j1 > LSEQ - 1) j1 = LSEQ - 1;
    for (int j = j0; j <= j1; ++j) {
        union { ushort4 u; bf16 h[4]; } rv;
        rv.u = *reinterpret_cast<const ushort4*>(&base[(size_t)j * DMODEL + c]);
        float4 v; v.x = f32(rv.h[0]); v.y = f32(rv.h[1]); v.z = f32(rv.h[2]); v.w = f32(rv.h[3]);
#pragma unroll
        for (int o = 0; o < 4; ++o) {
            const int lo = l0 + o;
            if (j >= lo - 12 && j <= lo + 12) {
                s[o].x += v.x; s[o].y += v.y; s[o].z += v.z; s[o].w += v.w;
            }
        }
    }
    const float kinv = 1.0f / 25.0f;
    float4 tr[4];
    float p1[4], p2[4];
#pragma unroll
    for (int o = 0; o < 4; ++o) {
        tr[o].x = s[o].x * kinv; tr[o].y = s[o].y * kinv;
        tr[o].z = s[o].z * kinv; tr[o].w = s[o].w * kinv;
        p1[o] = tr[o].x + tr[o].y + tr[o].z + tr[o].w;
        p2[o] = tr[o].x * tr[o].x + tr[o].y * tr[o].y + tr[o].z * tr[o].z + tr[o].w * tr[o].w;
    }
    const int lane = t & 63, wv = t >> 6;
#pragma unroll
    for (int off = 1; off < 64; off <<= 1) {
#pragma unroll
        for (int o = 0; o < 4; ++o) {
            p1[o] += __shfl_xor(p1[o], off);
            p2[o] += __shfl_xor(p2[o], off);
        }
    }
    __shared__ float red[4][8];
    if (lane == 0) {
#pragma unroll
        for (int o = 0; o < 4; ++o) { red[wv][o] = p1[o]; red[wv][4 + o] = p2[o]; }
    }
    __syncthreads();
    float4 gg = *reinterpret_cast<const float4*>(&g[c]);
    float4 bb = *reinterpret_cast<const float4*>(&be[c]);
#pragma unroll
    for (int o = 0; o < 4; ++o) {
        float q1 = red[0][o] + red[1][o] + red[2][o] + red[3][o];
        float q2 = red[0][4 + o] + red[1][4 + o] + red[2][4 + o] + red[3][4 + o];
        const float mu  = q1 * (1.0f / 1024.0f);
        const float var = q2 * (1.0f / 1024.0f) - mu * mu;
        const float inv = rsqrtf(var + 1e-5f);
        float o0 = (tr[o].x - mu) * inv * gg.x + bb.x;
        float o1 = (tr[o].y - mu) * inv * gg.y + bb.y;
        float o2 = (tr[o].z - mu) * inv * gg.z + bb.z;
        float o3 = (tr[o].w - mu) * inv * gg.w + bb.w;
        if (out) {
            float4 ov; ov.x = o0; ov.y = o1; ov.z = o2; ov.w = o3;
            *reinterpret_cast<float4*>(&out[(size_t)(row0 + o) * DMODEL + c]) = ov;
        }
        if (outb) {
            union { ushort4 u; bf16 hh[4]; } ob;
            ob.hh[0] = b16(o0); ob.hh[1] = b16(o1); ob.hh[2] = b16(o2); ob.hh[3] = b16(o3);
            reinterpret_cast<ushort4*>(outb + (size_t)(row0 + o) * DMODEL)[t] = ob.u;
        }
    }
}

extern "C" void kernel_launch(void* const* d_in, const int* in_sizes, int n_in,
                              void* d_out, int out_size, void* d_ws, size_t ws_size,
                              hipStream_t stream) {
    const float* x   = (const float*)d_in[0];
    const float* Wq  = (const float*)d_in[1];
    const float* bq  = (const float*)d_in[2];
    const float* Wk  = (const float*)d_in[3];
    const float* bk  = (const float*)d_in[4];
    const float* Wv  = (const float*)d_in[5];
    const float* bv  = (const float*)d_in[6];
    const float* Wo  = (const float*)d_in[7];
    const float* bo  = (const float*)d_in[8];
    const float* W1  = (const float*)d_in[9];
    const float* b1  = (const float*)d_in[10];
    const float* W2  = (const float*)d_in[11];
    const float* b2  = (const float*)d_in[12];
    const float* g1  = (const float*)d_in[13];
    const float* be1 = (const float*)d_in[14];
    const float* g2  = (const float*)d_in[15];
    const float* be2 = (const float*)d_in[16];
    float* out = (float*)d_out;
    char* ws = (char*)d_ws;
    const size_t MB = 1u << 20;

    // timeline-overlapped layout (152MB total):
    bf16* xb    = (bf16*)(ws + 0);         //  8MB  (1-2)
    bf16* rrb   = (bf16*)(ws + 8 * MB);    //  8MB  (5-6, 9-10)
    bf16* qkvb  = (bf16*)(ws + 16 * MB);   // 24MB  (2-3)
    bf16* ab    = (bf16*)(ws + 16 * MB);   //  8MB  (6-9; qkvb dead after attn)
    bf16* hb    = (bf16*)(ws + 24 * MB);   // 32MB  (7-8)
    bf16* aob   = (bf16*)(ws + 40 * MB);   //  8MB  (3-4)
    bf16* Wqkvb = (bf16*)(ws + 48 * MB);   //  6MB  (1-2)
    bf16* Wob   = (bf16*)(ws + 54 * MB);   //  2MB  (1-4)
    bf16* W1b   = (bf16*)(ws + 56 * MB);   //  8MB  (1-7)
    bf16* W2b   = (bf16*)(ws + 64 * MB);   //  8MB  (1-8)
    bf16* P     = (bf16*)(ws + 72 * MB);   // 32MB  bf16 partials (4 slices x 8MB)
    float* bqkv = (float*)(ws + 136 * MB); // 12KB  (1-2)

    // 1. all conversions + bias concat (one dispatch, 4 y-slices)
    f2b_all<<<dim3((MROWS * DMODEL / 4) / 256, 4), 256, 0, stream>>>(
        x, W1, W2, Wq, Wk, Wv, Wo, bq, bk, bv,
        xb, W1b, W2b, Wqkvb, Wob, bqkv);

    // 2. fused QKV projection -> qkvb [4096][3072]  (16x24 = 384 blocks)
    gemmT<2><<<dim3(384, 1, 1), 256, 0, stream>>>(xb, Wqkvb, bqkv, qkvb,
                                                  MROWS, 3 * DMODEL, DMODEL, DMODEL, DMODEL, 24);
    // 3. attention (banded +-1 tile)
    attn_kernel<<<dim3(32, 32), 256, 0, stream>>>(qkvb, qkvb + DMODEL, qkvb + 2 * DMODEL,
                                                  aob, 3 * DMODEL, DMODEL);
    // 4. output projection, split-K=2 -> P[0:2] (bf16)  (16x8 x2 = 256 blocks)
    gemmT<3><<<dim3(128, 1, 2), 256, 0, stream>>>(aob, Wob, nullptr, P,
                                                  MROWS, DMODEL, DMODEL, DMODEL, DMODEL / 2, 8);
    // 5. rrb = x + sum(P0,P1) + bo  (bf16 out)
    reduce_kernel<2, false><<<(MROWS * DMODEL / 4) / 256, 256, 0, stream>>>(
        x, P, bo, rrb, MROWS * DMODEL / 4);
    // 6. movavg + LN1 -> ab (bf16 only)
    mavg_ln4_kernel<<<MROWS / 4, 256, 0, stream>>>(rrb, g1, be1, nullptr, ab);
    // 7. FF1 (GELU, bf16 out)  (16x32 = 512 blocks)
    gemmT<1><<<dim3(512, 1, 1), 256, 0, stream>>>(ab, W1b, b1, hb,
                                                  MROWS, DFF, DMODEL, DMODEL, DMODEL, 32);
    // 8. FF2, split-K=4 -> P[0:4] (bf16)  (16x8 x4 = 512 blocks)
    gemmT<3><<<dim3(128, 1, 4), 256, 0, stream>>>(hb, W2b, nullptr, P,
                                                  MROWS, DMODEL, DFF, DFF, DFF / 4, 8);
    // 9. rrb = ab + sum(P0..P3) + b2  (bf16 residual in, bf16 out)
    reduce_kernel<4, true><<<(MROWS * DMODEL / 4) / 256, 256, 0, stream>>>(
        ab, P, b2, rrb, MROWS * DMODEL / 4);
    // 10. movavg + LN2 -> out (fp32)
    mavg_ln4_kernel<<<MROWS / 4, 256, 0, stream>>>(rrb, g2, be2, out, nullptr);
}

// Round 17
// 234.922 us; speedup vs baseline: 1.0093x; 1.0024x over previous
//
#include <hip/hip_runtime.h>
#include <hip/hip_bf16.h>
#include <math.h>

#define DMODEL 1024
#define LSEQ   2048
#define BATCH  2
#define NHEADS 16
#define DHEAD  64
#define DFF    4096
#define MROWS  (BATCH*LSEQ)   // 4096

typedef __attribute__((ext_vector_type(8))) short short8;
typedef __attribute__((ext_vector_type(4))) float f32x4;
using bf16 = __hip_bfloat16;

static __device__ __forceinline__ f32x4 mfma16(short8 a, short8 b, f32x4 c) {
    return __builtin_amdgcn_mfma_f32_16x16x32_bf16(a, b, c, 0, 0, 0);
}

static __device__ __forceinline__ void gload16(const void* g, void* l) {
    __builtin_amdgcn_global_load_lds(
        (const __attribute__((address_space(1))) char*)g,
        (__attribute__((address_space(3))) char*)l, 16, 0, 0);
}

static __device__ __forceinline__ bf16 b16(float v) { return __float2bfloat16(v); }
static __device__ __forceinline__ float f32(bf16 v) { return __bfloat162float(v); }

// ---------------- all fp32 -> bf16 conversions + bias concat, ONE dispatch --------
__global__ void f2b_all(const float* __restrict__ x, const float* __restrict__ W1,
                        const float* __restrict__ W2,
                        const float* Wq, const float* Wk, const float* Wv, const float* Wo,
                        const float* bq, const float* bk, const float* bv,
                        bf16* __restrict__ xb, bf16* __restrict__ W1b, bf16* __restrict__ W2b,
                        bf16* __restrict__ Wqkvb, bf16* __restrict__ Wob,
                        float* __restrict__ bqkv) {
    int i = blockIdx.x * blockDim.x + threadIdx.x;
    const float* in; bf16* out;
    switch (blockIdx.y) {
        case 0:
            in = x; out = xb;
            if (i < DMODEL / 4) {   // fold bias concat into the x-conversion slice
                reinterpret_cast<float4*>(bqkv)[i]                  = reinterpret_cast<const float4*>(bq)[i];
                reinterpret_cast<float4*>(bqkv)[DMODEL / 4 + i]     = reinterpret_cast<const float4*>(bk)[i];
                reinterpret_cast<float4*>(bqkv)[2 * DMODEL / 4 + i] = reinterpret_cast<const float4*>(bv)[i];
            }
            break;
        case 1: in = W1; out = W1b; break;
        case 2: in = W2; out = W2b; break;
        default: {
            const int w = i >> 18, r = i & ((1 << 18) - 1);   // 256K float4 per weight
            const float* ws4[4] = {Wq, Wk, Wv, Wo};
            bf16* os4[4] = {Wqkvb, Wqkvb + (DMODEL * DMODEL), Wqkvb + 2 * (DMODEL * DMODEL), Wob};
            float4 v = reinterpret_cast<const float4*>(ws4[w])[r];
            union { ushort4 u; bf16 h[4]; } o;
            o.h[0] = b16(v.x); o.h[1] = b16(v.y); o.h[2] = b16(v.z); o.h[3] = b16(v.w);
            reinterpret_cast<ushort4*>(os4[w])[r] = o.u;
            return;
        }
    }
    float4 v = reinterpret_cast<const float4*>(in)[i];
    union { ushort4 u; bf16 h[4]; } o;
    o.h[0] = b16(v.x); o.h[1] = b16(v.y); o.h[2] = b16(v.z); o.h[3] = b16(v.w);
    reinterpret_cast<ushort4*>(out)[i] = o.u;
}

// ------- split-K reduce: rr(bf16) = res + sum_s P_s(bf16) + bias -------------------
template<int S, bool RESB16>
__global__ __launch_bounds__(256) void reduce_kernel(const void* __restrict__ resv,
                                                     const bf16* __restrict__ P,
                                                     const float* __restrict__ bias,
                                                     bf16* __restrict__ outb, int n4) {
    int i = blockIdx.x * blockDim.x + threadIdx.x;
    if (i >= n4) return;
    float4 acc;
    if (RESB16) {
        union { ushort4 u; bf16 h[4]; } r;
        r.u = reinterpret_cast<const ushort4*>(resv)[i];
        acc.x = f32(r.h[0]); acc.y = f32(r.h[1]); acc.z = f32(r.h[2]); acc.w = f32(r.h[3]);
    } else {
        acc = reinterpret_cast<const float4*>(resv)[i];
    }
#pragma unroll
    for (int s = 0; s < S; ++s) {
        union { ushort4 u; bf16 h[4]; } p;
        p.u = reinterpret_cast<const ushort4*>(P)[i + (size_t)s * (MROWS * DMODEL / 4)];
        acc.x += f32(p.h[0]); acc.y += f32(p.h[1]);
        acc.z += f32(p.h[2]); acc.w += f32(p.h[3]);
    }
    float4 bs = reinterpret_cast<const float4*>(bias)[i & (DMODEL / 4 - 1)];
    union { ushort4 u; bf16 h[4]; } o;
    o.h[0] = b16(acc.x + bs.x); o.h[1] = b16(acc.y + bs.y);
    o.h[2] = b16(acc.z + bs.z); o.h[3] = b16(acc.w + bs.w);
    reinterpret_cast<ushort4*>(outb)[i] = o.u;
}

// ---------------- GEMM 256x128 tile, BK=32, ring-2, 8 waves (TLP play) -------------
// 512 threads = 8 waves (2M x 4N), wave tile 128x32 (acc[8][2]).  48 KB LDS ->
// 3 blocks/CU = 6 waves/SIMD: independently-phased co-resident blocks fill each
// other's ds-latency / load-wait stalls (m97/m114 mechanism).  Per-buffer layout:
// A 16KB [0,16384) + B 8KB [16384,24576); T2 swizzle via pre-swizzled global
// source + matching XOR on ds_read (verified mapping).
// EPI: 0 fp32+bias, 1 GELU+bf16, 2 bf16+bias, 3 bf16 partial (blockIdx.z = k-slice)
template<int EPI>
__global__ __launch_bounds__(512, 4) void gemmT(const bf16* __restrict__ A,
                                                const bf16* __restrict__ W,
                                                const float* __restrict__ bias,
                                                void* __restrict__ Cout,
                                                int M, int N, int lda, int ldw,
                                                int K, int nn) {
    __shared__ bf16 sm[24576];   // 2 bufs x (A 16KB | B 8KB) = 48 KB
    const int t    = threadIdx.x;
    const int wave = t >> 6, lane = t & 63;
    const int lr   = lane & 15, lkb = lane >> 4;
    const int wm   = wave >> 2, wn = wave & 3;
    const int sk   = blockIdx.z;

    // XCD-aware bijective swizzle (all gridDim.x % 8 == 0)
    const int nwg = gridDim.x;
    const int bid = blockIdx.x;
    const int wg  = (bid & 7) * (nwg >> 3) + (bid >> 3);
    const int m0  = (wg / nn) * 256;
    const int n0  = (wg % nn) * 128;

    // staging: 3 gload16 per K-tile per thread (A: u=0,1 -> 1024 slots; B: u=2 -> 512)
    const bf16* src[3];
    int dbase[3];
#pragma unroll
    for (int u = 0; u < 3; ++u) {
        const int q  = (u < 2) ? (u * 512 + t) : t;     // 16B-slot index in region
        const int R  = q >> 3;                          // 128B super-row
        const int ss = (q & 7) ^ (R & 7);
        const int rp = ss >> 2, c = (ss & 3) * 8;
        if (u < 2) {
            src[u]   = A + (size_t)(m0 + 2 * R + rp) * lda + (size_t)sk * K + c;
            dbase[u] = u * 8192 + wave * 1024;          // wave-uniform; HW adds lane*16
        } else {
            src[u]   = W + (size_t)(n0 + 2 * R + rp) * ldw + (size_t)sk * K + c;
            dbase[u] = 16384 + wave * 1024;
        }
    }
    char* smb = (char*)sm;

    // ds_read byte offsets (XOR-swizzled; 2 lanes/bank = free)
    int aoff[8], boff[2];
#pragma unroll
    for (int i = 0; i < 8; ++i) {
        const int r = wm * 128 + i * 16 + lr, R = r >> 1;
        aoff[i] = R * 128 + ((((r & 1) << 2) | lkb) ^ (R & 7)) * 16;
    }
#pragma unroll
    for (int j = 0; j < 2; ++j) {
        const int r = wn * 32 + j * 16 + lr, R = r >> 1;
        boff[j] = 16384 + R * 128 + ((((r & 1) << 2) | lkb) ^ (R & 7)) * 16;
    }

    f32x4 acc[8][2];
#pragma unroll
    for (int i = 0; i < 8; ++i)
#pragma unroll
        for (int j = 0; j < 2; ++j)
            acc[i][j] = (f32x4){0.f, 0.f, 0.f, 0.f};

    const int nt = K >> 5;
    auto STAGE = [&](int bufoff, int kt) {
        const int koff = kt * 32;
#pragma unroll
        for (int u = 0; u < 3; ++u)
            gload16(src[u] + koff, smb + bufoff + dbase[u]);
    };

    // prologue: tile0 only; drain and go
    STAGE(0, 0);
    __builtin_amdgcn_sched_barrier(0);
    asm volatile("s_waitcnt vmcnt(0)" ::: "memory");
    __builtin_amdgcn_s_barrier();
    __builtin_amdgcn_sched_barrier(0);

    int cur = 0;
    for (int kt = 0; kt < nt; ++kt) {
        if (kt + 1 < nt) STAGE((cur ^ 1) * 24576, kt + 1);   // issue early, land late
        short8 a[8], b[2];
#pragma unroll
        for (int i = 0; i < 8; ++i)
            a[i] = *reinterpret_cast<const short8*>(smb + cur * 24576 + aoff[i]);
#pragma unroll
        for (int j = 0; j < 2; ++j)
            b[j] = *reinterpret_cast<const short8*>(smb + cur * 24576 + boff[j]);
        __builtin_amdgcn_s_setprio(1);
#pragma unroll
        for (int i = 0; i < 8; ++i)
#pragma unroll
            for (int j = 0; j < 2; ++j)
                acc[i][j] = mfma16(b[j], a[i], acc[i][j]);   // swapped operands
        __builtin_amdgcn_s_setprio(0);
        __builtin_amdgcn_sched_barrier(0);
        asm volatile("s_waitcnt vmcnt(0)" ::: "memory");     // next tile landed
        __builtin_amdgcn_s_barrier();
        __builtin_amdgcn_sched_barrier(0);
        cur ^= 1;
    }

    // epilogue: row = m0+wm*128+i*16+lr, cols = n0+wn*32+j*16+lkb*4 + 0..3
#pragma unroll
    for (int i = 0; i < 8; ++i) {
        const int row = m0 + wm * 128 + i * 16 + lr;
#pragma unroll
        for (int j = 0; j < 2; ++j) {
            const int col = n0 + wn * 32 + j * 16 + lkb * 4;
            f32x4 v = acc[i][j];
            if (EPI != 3) {
                float4 bs = *reinterpret_cast<const float4*>(&bias[col]);
                v[0] += bs.x; v[1] += bs.y; v[2] += bs.z; v[3] += bs.w;
            }
            if (EPI == 0) {
                float4 ov; ov.x = v[0]; ov.y = v[1]; ov.z = v[2]; ov.w = v[3];
                *reinterpret_cast<float4*>(&((float*)Cout)[(size_t)row * N + col]) = ov;
            } else if (EPI == 1) {
                union { ushort4 u; bf16 h[4]; } ob;
#pragma unroll
                for (int q = 0; q < 4; ++q) {
                    float x = v[q];
                    float u2 = x * (1.5957691216f + 0.0713548162f * x * x);
                    float e = __expf(fminf(u2, 60.f));
                    ob.h[q] = b16(x * (e / (e + 1.f)));   // x*sigmoid(2u) GELU
                }
                *reinterpret_cast<ushort4*>(
                    &reinterpret_cast<bf16*>(Cout)[(size_t)row * N + col]) = ob.u;
            } else if (EPI == 2) {
                union { ushort4 u; bf16 h[4]; } ob;
#pragma unroll
                for (int q = 0; q < 4; ++q) ob.h[q] = b16(v[q]);
                *reinterpret_cast<ushort4*>(
                    &reinterpret_cast<bf16*>(Cout)[(size_t)row * N + col]) = ob.u;
            } else {
                bf16* Pp = (bf16*)Cout + (size_t)sk * M * N;
                union { ushort4 u; bf16 h[4]; } ob;
#pragma unroll
                for (int q = 0; q < 4; ++q) ob.h[q] = b16(v[q]);
                *reinterpret_cast<ushort4*>(&Pp[(size_t)row * N + col]) = ob.u;
            }
        }
    }
}

// ---------------- fused attention (flash-style, bf16 MFMA, banded +-1 tile) -------
__global__ __launch_bounds__(256) void attn_kernel(const bf16* __restrict__ Q,
                                                   const bf16* __restrict__ Km,
                                                   const bf16* __restrict__ V,
                                                   bf16* __restrict__ O,
                                                   int ldq, int ldo) {
    __shared__ bf16 Qs[64][72];
    __shared__ bf16 Ks[64][72];
    __shared__ bf16 VsT[64][72];   // transposed V tile: VsT[d][m]
    __shared__ bf16 Ps[64][72];
    const int t    = threadIdx.x;
    const int wave = t >> 6, lane = t & 63;
    const int lr   = lane & 15, lkb = lane >> 4;
    const int qt   = blockIdx.x;
    const int q0   = qt * 64;
    const int b    = blockIdx.y >> 4, h = blockIdx.y & 15;
    const size_t base  = (size_t)b * LSEQ * ldq + (size_t)h * DHEAD;
    const size_t baseo = (size_t)b * LSEQ * ldo + (size_t)h * DHEAD;

#pragma unroll
    for (int p = 0; p < 2; ++p) {
        int idx = t + p * 256;
        int row = idx >> 3, c = (idx & 7) * 8;
        *reinterpret_cast<uint4*>(&Qs[row][c]) =
            *reinterpret_cast<const uint4*>(&Q[base + (size_t)(q0 + row) * ldq + c]);
    }
    __syncthreads();
    short8 qa[2];
    qa[0] = *reinterpret_cast<const short8*>(&Qs[wave * 16 + lr][lkb * 8]);
    qa[1] = *reinterpret_cast<const short8*>(&Qs[wave * 16 + lr][32 + lkb * 8]);

    f32x4 o[4];
#pragma unroll
    for (int dj = 0; dj < 4; ++dj) o[dj] = (f32x4){0.f, 0.f, 0.f, 0.f};
    float mrun[4], lrun[4];
#pragma unroll
    for (int q = 0; q < 4; ++q) { mrun[q] = -1e30f; lrun[q] = 0.f; }

    int kt0 = qt - 1; if (kt0 < 0) kt0 = 0;
    int kt1 = qt + 1; if (kt1 > LSEQ / 64 - 1) kt1 = LSEQ / 64 - 1;

    for (int kt = kt0; kt <= kt1; ++kt) {
        const int k0 = kt * 64;
        __syncthreads();
#pragma unroll
        for (int p = 0; p < 2; ++p) {
            int idx = t + p * 256;
            int row = idx >> 3, c = (idx & 7) * 8;
            *reinterpret_cast<uint4*>(&Ks[row][c]) =
                *reinterpret_cast<const uint4*>(&Km[base + (size_t)(k0 + row) * ldq + c]);
        }
        {
            const int vl = lane, vw = wave;
#pragma unroll
            for (int p = 0; p < 2; ++p) {
                int c = vw * 8 + p * 32;
                union { uint4 u; bf16 hh[8]; } tv;
                tv.u = *reinterpret_cast<const uint4*>(&V[base + (size_t)(k0 + vl) * ldq + c]);
#pragma unroll
                for (int e = 0; e < 8; ++e) VsT[c + e][vl] = tv.hh[e];
            }
        }
        __syncthreads();

        f32x4 s[4];
#pragma unroll
        for (int j = 0; j < 4; ++j) {
            short8 kb0 = *reinterpret_cast<const short8*>(&Ks[j * 16 + lr][lkb * 8]);
            short8 kb1 = *reinterpret_cast<const short8*>(&Ks[j * 16 + lr][32 + lkb * 8]);
            f32x4 z = (f32x4){0.f, 0.f, 0.f, 0.f};
            z = mfma16(qa[0], kb0, z);
            z = mfma16(qa[1], kb1, z);
            s[j] = z;
        }
        float mx[4];
#pragma unroll
        for (int q = 0; q < 4; ++q) mx[q] = -1e30f;
#pragma unroll
        for (int j = 0; j < 4; ++j) {
            int cm = k0 + j * 16 + lr;
#pragma unroll
            for (int q = 0; q < 4; ++q) {
                int rq = q0 + wave * 16 + lkb * 4 + q;
                float sv = s[j][q] * 0.125f - 0.1f * fabsf((float)(rq - cm));
                s[j][q] = sv;
                mx[q] = fmaxf(mx[q], sv);
            }
        }
#pragma unroll
        for (int q = 0; q < 4; ++q) {
#pragma unroll
            for (int off = 1; off < 16; off <<= 1)
                mx[q] = fmaxf(mx[q], __shfl_xor(mx[q], off));
        }
        float alpha[4];
#pragma unroll
        for (int q = 0; q < 4; ++q) {
            float mnew = fmaxf(mrun[q], mx[q]);
            alpha[q] = __expf(mrun[q] - mnew);
            mrun[q] = mnew;
        }
        float rs[4] = {0.f, 0.f, 0.f, 0.f};
#pragma unroll
        for (int j = 0; j < 4; ++j) {
#pragma unroll
            for (int q = 0; q < 4; ++q) {
                float p = __expf(s[j][q] - mrun[q]);
                rs[q] += p;
                Ps[wave * 16 + lkb * 4 + q][j * 16 + lr] = b16(p);
            }
        }
#pragma unroll
        for (int q = 0; q < 4; ++q) {
#pragma unroll
            for (int off = 1; off < 16; off <<= 1)
                rs[q] += __shfl_xor(rs[q], off);
            lrun[q] = lrun[q] * alpha[q] + rs[q];
        }
#pragma unroll
        for (int dj = 0; dj < 4; ++dj)
#pragma unroll
            for (int q = 0; q < 4; ++q) o[dj][q] *= alpha[q];
        // no barrier: Ps rows are wave-private

        short8 pa0 = *reinterpret_cast<const short8*>(&Ps[wave * 16 + lr][lkb * 8]);
        short8 pa1 = *reinterpret_cast<const short8*>(&Ps[wave * 16 + lr][32 + lkb * 8]);
#pragma unroll
        for (int dj = 0; dj < 4; ++dj) {
            short8 vb0 = *reinterpret_cast<const short8*>(&VsT[dj * 16 + lr][lkb * 8]);
            short8 vb1 = *reinterpret_cast<const short8*>(&VsT[dj * 16 + lr][32 + lkb * 8]);
            o[dj] = mfma16(pa0, vb0, o[dj]);
            o[dj] = mfma16(pa1, vb1, o[dj]);
        }
    }

#pragma unroll
    for (int dj = 0; dj < 4; ++dj) {
#pragma unroll
        for (int q = 0; q < 4; ++q) {
            int row = q0 + wave * 16 + lkb * 4 + q;
            int col = dj * 16 + lr;
            float val = o[dj][q] / lrun[q];
            O[baseo + (size_t)row * ldo + col] = b16(val);
        }
    }
}

// ------- moving average (k=25) + LayerNorm, 4 rows/block, XCD-chunked, bf16 in -----
__global__ __launch_bounds__(256) void mavg_ln4_kernel(const bf16* __restrict__ r,
                                                       const float* __restrict__ g,
                                                       const float* __restrict__ be,
                                                       float* __restrict__ out,
                                                       bf16* __restrict__ outb) {
    const int gid = (blockIdx.x & 7) * (MROWS / 8 / 4) + (blockIdx.x >> 3); // bijective
    const int row0 = gid * 4;
    const int b = row0 >> 11, l0 = row0 & 2047;
    const int t = threadIdx.x, c = t * 4;
    const bf16* base = r + (size_t)b * LSEQ * DMODEL;

    float4 s[4];
#pragma unroll
    for (int o = 0; o < 4; ++o) s[o] = (float4){0.f, 0.f, 0.f, 0.f};
    int j0 = l0 - 12; if (j0 < 0) j0 = 0;
    int j1 = l0 + 15; if (j1 > LSEQ - 1) j1 = LSEQ - 1;
    for (int j = j0; j <= j1; ++j) {
        union { ushort4 u; bf16 h[4]; } rv;
        rv.u = *reinterpret_cast<const ushort4*>(&base[(size_t)j * DMODEL + c]);
        float4 v; v.x = f32(rv.h[0]); v.y = f32(rv.h[1]); v.z = f32(rv.h[2]); v.w = f32(rv.h[3]);
#pragma unroll
        for (int o = 0; o < 4; ++o) {
            const int lo = l0 + o;
            if (j >= lo - 12 && j <= lo + 12) {
                s[o].x += v.x; s[o].y += v.y; s[o].z += v.z; s[o].w += v.w;
            }
        }
    }
    const float kinv = 1.0f / 25.0f;
    float4 tr[4];
    float p1[4], p2[4];
#pragma unroll
    for (int o = 0; o < 4; ++o) {
        tr[o].x = s[o].x * kinv; tr[o].y = s[o].y * kinv;
        tr[o].z = s[o].z * kinv; tr[o].w = s[o].w * kinv;
        p1[o] = tr[o].x + tr[o].y + tr[o].z + tr[o].w;
        p2[o] = tr[o].x * tr[o].x + tr[o].y * tr[o].y + tr[o].z * tr[o].z + tr[o].w * tr[o].w;
    }
    const int lane = t & 63, wv = t >> 6;
#pragma unroll
    for (int off = 1; off < 64; off <<= 1) {
#pragma unroll
        for (int o = 0; o < 4; ++o) {
            p1[o] += __shfl_xor(p1[o], off);
            p2[o] += __shfl_xor(p2[o], off);
        }
    }
    __shared__ float red[4][8];
    if (lane == 0) {
#pragma unroll
        for (int o = 0; o < 4; ++o) { red[wv][o] = p1[o]; red[wv][4 + o] = p2[o]; }
    }
    __syncthreads();
    float4 gg = *reinterpret_cast<const float4*>(&g[c]);
    float4 bb = *reinterpret_cast<const float4*>(&be[c]);
#pragma unroll
    for (int o = 0; o < 4; ++o) {
        float q1 = red[0][o] + red[1][o] + red[2][o] + red[3][o];
        float q2 = red[0][4 + o] + red[1][4 + o] + red[2][4 + o] + red[3][4 + o];
        const float mu  = q1 * (1.0f / 1024.0f);
        const float var = q2 * (1.0f / 1024.0f) - mu * mu;
        const float inv = rsqrtf(var + 1e-5f);
        float o0 = (tr[o].x - mu) * inv * gg.x + bb.x;
        float o1 = (tr[o].y - mu) * inv * gg.y + bb.y;
        float o2 = (tr[o].z - mu) * inv * gg.z + bb.z;
        float o3 = (tr[o].w - mu) * inv * gg.w + bb.w;
        if (out) {
            float4 ov; ov.x = o0; ov.y = o1; ov.z = o2; ov.w = o3;
            *reinterpret_cast<float4*>(&out[(size_t)(row0 + o) * DMODEL + c]) = ov;
        }
        if (outb) {
            union { ushort4 u; bf16 hh[4]; } ob;
            ob.hh[0] = b16(o0); ob.hh[1] = b16(o1); ob.hh[2] = b16(o2); ob.hh[3] = b16(o3);
            reinterpret_cast<ushort4*>(outb + (size_t)(row0 + o) * DMODEL)[t] = ob.u;
        }
    }
}

extern "C" void kernel_launch(void* const* d_in, const int* in_sizes, int n_in,
                              void* d_out, int out_size, void* d_ws, size_t ws_size,
                              hipStream_t stream) {
    const float* x   = (const float*)d_in[0];
    const float* Wq  = (const float*)d_in[1];
    const float* bq  = (const float*)d_in[2];
    const float* Wk  = (const float*)d_in[3];
    const float* bk  = (const float*)d_in[4];
    const float* Wv  = (const float*)d_in[5];
    const float* bv  = (const float*)d_in[6];
    const float* Wo  = (const float*)d_in[7];
    const float* bo  = (const float*)d_in[8];
    const float* W1  = (const float*)d_in[9];
    const float* b1  = (const float*)d_in[10];
    const float* W2  = (const float*)d_in[11];
    const float* b2  = (const float*)d_in[12];
    const float* g1  = (const float*)d_in[13];
    const float* be1 = (const float*)d_in[14];
    const float* g2  = (const float*)d_in[15];
    const float* be2 = (const float*)d_in[16];
    float* out = (float*)d_out;
    char* ws = (char*)d_ws;
    const size_t MB = 1u << 20;

    // timeline-overlapped layout (152MB total):
    bf16* xb    = (bf16*)(ws + 0);         //  8MB  (1-2)
    bf16* rrb   = (bf16*)(ws + 8 * MB);    //  8MB  (5-6, 9-10)
    bf16* qkvb  = (bf16*)(ws + 16 * MB);   // 24MB  (2-3)
    bf16* ab    = (bf16*)(ws + 16 * MB);   //  8MB  (6-9; qkvb dead after attn)
    bf16* hb    = (bf16*)(ws + 24 * MB);   // 32MB  (7-8)
    bf16* aob   = (bf16*)(ws + 40 * MB);   //  8MB  (3-4)
    bf16* Wqkvb = (bf16*)(ws + 48 * MB);   //  6MB  (1-2)
    bf16* Wob   = (bf16*)(ws + 54 * MB);   //  2MB  (1-4)
    bf16* W1b   = (bf16*)(ws + 56 * MB);   //  8MB  (1-7)
    bf16* W2b   = (bf16*)(ws + 64 * MB);   //  8MB  (1-8)
    bf16* P     = (bf16*)(ws + 72 * MB);   // 32MB  bf16 partials (4 slices x 8MB)
    float* bqkv = (float*)(ws + 136 * MB); // 12KB  (1-2)

    // 1. all conversions + bias concat (one dispatch, 4 y-slices)
    f2b_all<<<dim3((MROWS * DMODEL / 4) / 256, 4), 256, 0, stream>>>(
        x, W1, W2, Wq, Wk, Wv, Wo, bq, bk, bv,
        xb, W1b, W2b, Wqkvb, Wob, bqkv);

    // 2. fused QKV projection -> qkvb [4096][3072]  (16x24 = 384 blocks)
    gemmT<2><<<dim3(384, 1, 1), 512, 0, stream>>>(xb, Wqkvb, bqkv, qkvb,
                                                  MROWS, 3 * DMODEL, DMODEL, DMODEL, DMODEL, 24);
    // 3. attention (banded +-1 tile)
    attn_kernel<<<dim3(32, 32), 256, 0, stream>>>(qkvb, qkvb + DMODEL, qkvb + 2 * DMODEL,
                                                  aob, 3 * DMODEL, DMODEL);
    // 4. output projection, split-K=2 -> P[0:2] (bf16)  (16x8 x2 = 256 blocks)
    gemmT<3><<<dim3(128, 1, 2), 512, 0, stream>>>(aob, Wob, nullptr, P,
                                                  MROWS, DMODEL, DMODEL, DMODEL, DMODEL / 2, 8);
    // 5. rrb = x + sum(P0,P1) + bo  (bf16 out)
    reduce_kernel<2, false><<<(MROWS * DMODEL / 4) / 256, 256, 0, stream>>>(
        x, P, bo, rrb, MROWS * DMODEL / 4);
    // 6. movavg + LN1 -> ab (bf16 only)
    mavg_ln4_kernel<<<MROWS / 4, 256, 0, stream>>>(rrb, g1, be1, nullptr, ab);
    // 7. FF1 (GELU, bf16 out)  (16x32 = 512 blocks)
    gemmT<1><<<dim3(512, 1, 1), 512, 0, stream>>>(ab, W1b, b1, hb,
                                                  MROWS, DFF, DMODEL, DMODEL, DMODEL, 32);
    // 8. FF2, split-K=4 -> P[0:4] (bf16)  (16x8 x4 = 512 blocks)
    gemmT<3><<<dim3(128, 1, 4), 512, 0, stream>>>(hb, W2b, nullptr, P,
                                                  MROWS, DMODEL, DFF, DFF, DFF / 4, 8);
    // 9. rrb = ab + sum(P0..P3) + b2  (bf16 residual in, bf16 out)
    reduce_kernel<4, true><<<(MROWS * DMODEL / 4) / 256, 256, 0, stream>>>(
        ab, P, b2, rrb, MROWS * DMODEL / 4);
    // 10. movavg + LN2 -> out (fp32)
    mavg_ln4_kernel<<<MROWS / 4, 256, 0, stream>>>(rrb, g2, be2, out, nullptr);
}

// Round 18
// 233.838 us; speedup vs baseline: 1.0140x; 1.0046x over previous
//
#include <hip/hip_runtime.h>
#include <hip/hip_bf16.h>
#include <math.h>

#define DMODEL 1024
#define LSEQ   2048
#define BATCH  2
#define NHEADS 16
#define DHEAD  64
#define DFF    4096
#define MROWS  (BATCH*LSEQ)   // 4096

typedef __attribute__((ext_vector_type(8))) short short8;
typedef __attribute__((ext_vector_type(4))) float f32x4;
using bf16 = __hip_bfloat16;

static __device__ __forceinline__ f32x4 mfma16(short8 a, short8 b, f32x4 c) {
    return __builtin_amdgcn_mfma_f32_16x16x32_bf16(a, b, c, 0, 0, 0);
}

static __device__ __forceinline__ void gload16(const void* g, void* l) {
    __builtin_amdgcn_global_load_lds(
        (const __attribute__((address_space(1))) char*)g,
        (__attribute__((address_space(3))) char*)l, 16, 0, 0);
}

static __device__ __forceinline__ bf16 b16(float v) { return __float2bfloat16(v); }
static __device__ __forceinline__ float f32(bf16 v) { return __bfloat162float(v); }

// ---------------- all fp32 -> bf16 conversions + bias concat, ONE dispatch --------
__global__ void f2b_all(const float* __restrict__ x, const float* __restrict__ W1,
                        const float* __restrict__ W2,
                        const float* Wq, const float* Wk, const float* Wv, const float* Wo,
                        const float* bq, const float* bk, const float* bv,
                        bf16* __restrict__ xb, bf16* __restrict__ W1b, bf16* __restrict__ W2b,
                        bf16* __restrict__ Wqkvb, bf16* __restrict__ Wob,
                        float* __restrict__ bqkv) {
    int i = blockIdx.x * blockDim.x + threadIdx.x;
    const float* in; bf16* out;
    switch (blockIdx.y) {
        case 0:
            in = x; out = xb;
            if (i < DMODEL / 4) {   // fold bias concat into the x-conversion slice
                reinterpret_cast<float4*>(bqkv)[i]                  = reinterpret_cast<const float4*>(bq)[i];
                reinterpret_cast<float4*>(bqkv)[DMODEL / 4 + i]     = reinterpret_cast<const float4*>(bk)[i];
                reinterpret_cast<float4*>(bqkv)[2 * DMODEL / 4 + i] = reinterpret_cast<const float4*>(bv)[i];
            }
            break;
        case 1: in = W1; out = W1b; break;
        case 2: in = W2; out = W2b; break;
        default: {
            const int w = i >> 18, r = i & ((1 << 18) - 1);   // 256K float4 per weight
            const float* ws4[4] = {Wq, Wk, Wv, Wo};
            bf16* os4[4] = {Wqkvb, Wqkvb + (DMODEL * DMODEL), Wqkvb + 2 * (DMODEL * DMODEL), Wob};
            float4 v = reinterpret_cast<const float4*>(ws4[w])[r];
            union { ushort4 u; bf16 h[4]; } o;
            o.h[0] = b16(v.x); o.h[1] = b16(v.y); o.h[2] = b16(v.z); o.h[3] = b16(v.w);
            reinterpret_cast<ushort4*>(os4[w])[r] = o.u;
            return;
        }
    }
    float4 v = reinterpret_cast<const float4*>(in)[i];
    union { ushort4 u; bf16 h[4]; } o;
    o.h[0] = b16(v.x); o.h[1] = b16(v.y); o.h[2] = b16(v.z); o.h[3] = b16(v.w);
    reinterpret_cast<ushort4*>(out)[i] = o.u;
}

// ------- split-K reduce: rr(bf16) = res + sum_s P_s(bf16) + bias -------------------
template<int S, bool RESB16>
__global__ __launch_bounds__(256) void reduce_kernel(const void* __restrict__ resv,
                                                     const bf16* __restrict__ P,
                                                     const float* __restrict__ bias,
                                                     bf16* __restrict__ outb, int n4) {
    int i = blockIdx.x * blockDim.x + threadIdx.x;
    if (i >= n4) return;
    float4 acc;
    if (RESB16) {
        union { ushort4 u; bf16 h[4]; } r;
        r.u = reinterpret_cast<const ushort4*>(resv)[i];
        acc.x = f32(r.h[0]); acc.y = f32(r.h[1]); acc.z = f32(r.h[2]); acc.w = f32(r.h[3]);
    } else {
        acc = reinterpret_cast<const float4*>(resv)[i];
    }
#pragma unroll
    for (int s = 0; s < S; ++s) {
        union { ushort4 u; bf16 h[4]; } p;
        p.u = reinterpret_cast<const ushort4*>(P)[i + (size_t)s * (MROWS * DMODEL / 4)];
        acc.x += f32(p.h[0]); acc.y += f32(p.h[1]);
        acc.z += f32(p.h[2]); acc.w += f32(p.h[3]);
    }
    float4 bs = reinterpret_cast<const float4*>(bias)[i & (DMODEL / 4 - 1)];
    union { ushort4 u; bf16 h[4]; } o;
    o.h[0] = b16(acc.x + bs.x); o.h[1] = b16(acc.y + bs.y);
    o.h[2] = b16(acc.z + bs.z); o.h[3] = b16(acc.w + bs.w);
    reinterpret_cast<ushort4*>(outb)[i] = o.u;
}

// ---------------- GEMM 256x128 tile, BK=32, ring-2, 8 waves (R17 frozen) -----------
// 512 threads = 8 waves (2M x 4N), wave tile 128x32 (acc[8][2]).  48 KB LDS.
// Structural plateau note: 8 schedule/occupancy variants all land at 48-50us per
// big dispatch (~715 TF, MfmaUtil ~28%); plateau is TLP-insensitive (R17:
// occupancy 17->32% with no time change).  Escape requires m201-class 8-phase
// with derived waits (needs race screening unavailable here).  FROZEN.
// EPI: 0 fp32+bias, 1 GELU+bf16, 2 bf16+bias, 3 bf16 partial (blockIdx.z = k-slice)
template<int EPI>
__global__ __launch_bounds__(512, 4) void gemmT(const bf16* __restrict__ A,
                                                const bf16* __restrict__ W,
                                                const float* __restrict__ bias,
                                                void* __restrict__ Cout,
                                                int M, int N, int lda, int ldw,
                                                int K, int nn) {
    __shared__ bf16 sm[24576];   // 2 bufs x (A 16KB | B 8KB) = 48 KB
    const int t    = threadIdx.x;
    const int wave = t >> 6, lane = t & 63;
    const int lr   = lane & 15, lkb = lane >> 4;
    const int wm   = wave >> 2, wn = wave & 3;
    const int sk   = blockIdx.z;

    // XCD-aware bijective swizzle (all gridDim.x % 8 == 0)
    const int nwg = gridDim.x;
    const int bid = blockIdx.x;
    const int wg  = (bid & 7) * (nwg >> 3) + (bid >> 3);
    const int m0  = (wg / nn) * 256;
    const int n0  = (wg % nn) * 128;

    // staging: 3 gload16 per K-tile per thread (A: u=0,1 -> 1024 slots; B: u=2 -> 512)
    const bf16* src[3];
    int dbase[3];
#pragma unroll
    for (int u = 0; u < 3; ++u) {
        const int q  = (u < 2) ? (u * 512 + t) : t;     // 16B-slot index in region
        const int R  = q >> 3;                          // 128B super-row
        const int ss = (q & 7) ^ (R & 7);
        const int rp = ss >> 2, c = (ss & 3) * 8;
        if (u < 2) {
            src[u]   = A + (size_t)(m0 + 2 * R + rp) * lda + (size_t)sk * K + c;
            dbase[u] = u * 8192 + wave * 1024;          // wave-uniform; HW adds lane*16
        } else {
            src[u]   = W + (size_t)(n0 + 2 * R + rp) * ldw + (size_t)sk * K + c;
            dbase[u] = 16384 + wave * 1024;
        }
    }
    char* smb = (char*)sm;

    // ds_read byte offsets (XOR-swizzled; 2 lanes/bank = free)
    int aoff[8], boff[2];
#pragma unroll
    for (int i = 0; i < 8; ++i) {
        const int r = wm * 128 + i * 16 + lr, R = r >> 1;
        aoff[i] = R * 128 + ((((r & 1) << 2) | lkb) ^ (R & 7)) * 16;
    }
#pragma unroll
    for (int j = 0; j < 2; ++j) {
        const int r = wn * 32 + j * 16 + lr, R = r >> 1;
        boff[j] = 16384 + R * 128 + ((((r & 1) << 2) | lkb) ^ (R & 7)) * 16;
    }

    f32x4 acc[8][2];
#pragma unroll
    for (int i = 0; i < 8; ++i)
#pragma unroll
        for (int j = 0; j < 2; ++j)
            acc[i][j] = (f32x4){0.f, 0.f, 0.f, 0.f};

    const int nt = K >> 5;
    auto STAGE = [&](int bufoff, int kt) {
        const int koff = kt * 32;
#pragma unroll
        for (int u = 0; u < 3; ++u)
            gload16(src[u] + koff, smb + bufoff + dbase[u]);
    };

    // prologue: tile0 only; drain and go
    STAGE(0, 0);
    __builtin_amdgcn_sched_barrier(0);
    asm volatile("s_waitcnt vmcnt(0)" ::: "memory");
    __builtin_amdgcn_s_barrier();
    __builtin_amdgcn_sched_barrier(0);

    int cur = 0;
    for (int kt = 0; kt < nt; ++kt) {
        if (kt + 1 < nt) STAGE((cur ^ 1) * 24576, kt + 1);   // issue early, land late
        short8 a[8], b[2];
#pragma unroll
        for (int i = 0; i < 8; ++i)
            a[i] = *reinterpret_cast<const short8*>(smb + cur * 24576 + aoff[i]);
#pragma unroll
        for (int j = 0; j < 2; ++j)
            b[j] = *reinterpret_cast<const short8*>(smb + cur * 24576 + boff[j]);
        __builtin_amdgcn_s_setprio(1);
#pragma unroll
        for (int i = 0; i < 8; ++i)
#pragma unroll
            for (int j = 0; j < 2; ++j)
                acc[i][j] = mfma16(b[j], a[i], acc[i][j]);   // swapped operands
        __builtin_amdgcn_s_setprio(0);
        __builtin_amdgcn_sched_barrier(0);
        asm volatile("s_waitcnt vmcnt(0)" ::: "memory");     // next tile landed
        __builtin_amdgcn_s_barrier();
        __builtin_amdgcn_sched_barrier(0);
        cur ^= 1;
    }

    // epilogue: row = m0+wm*128+i*16+lr, cols = n0+wn*32+j*16+lkb*4 + 0..3
#pragma unroll
    for (int i = 0; i < 8; ++i) {
        const int row = m0 + wm * 128 + i * 16 + lr;
#pragma unroll
        for (int j = 0; j < 2; ++j) {
            const int col = n0 + wn * 32 + j * 16 + lkb * 4;
            f32x4 v = acc[i][j];
            if (EPI != 3) {
                float4 bs = *reinterpret_cast<const float4*>(&bias[col]);
                v[0] += bs.x; v[1] += bs.y; v[2] += bs.z; v[3] += bs.w;
            }
            if (EPI == 0) {
                float4 ov; ov.x = v[0]; ov.y = v[1]; ov.z = v[2]; ov.w = v[3];
                *reinterpret_cast<float4*>(&((float*)Cout)[(size_t)row * N + col]) = ov;
            } else if (EPI == 1) {
                union { ushort4 u; bf16 h[4]; } ob;
#pragma unroll
                for (int q = 0; q < 4; ++q) {
                    float x = v[q];
                    float u2 = x * (1.5957691216f + 0.0713548162f * x * x);
                    float e = __expf(fminf(u2, 60.f));
                    ob.h[q] = b16(x * (e / (e + 1.f)));   // x*sigmoid(2u) GELU
                }
                *reinterpret_cast<ushort4*>(
                    &reinterpret_cast<bf16*>(Cout)[(size_t)row * N + col]) = ob.u;
            } else if (EPI == 2) {
                union { ushort4 u; bf16 h[4]; } ob;
#pragma unroll
                for (int q = 0; q < 4; ++q) ob.h[q] = b16(v[q]);
                *reinterpret_cast<ushort4*>(
                    &reinterpret_cast<bf16*>(Cout)[(size_t)row * N + col]) = ob.u;
            } else {
                bf16* Pp = (bf16*)Cout + (size_t)sk * M * N;
                union { ushort4 u; bf16 h[4]; } ob;
#pragma unroll
                for (int q = 0; q < 4; ++q) ob.h[q] = b16(v[q]);
                *reinterpret_cast<ushort4*>(&Pp[(size_t)row * N + col]) = ob.u;
            }
        }
    }
}

// ---------------- fused attention (flash-style, bf16 MFMA, banded +-1 tile) -------
__global__ __launch_bounds__(256) void attn_kernel(const bf16* __restrict__ Q,
                                                   const bf16* __restrict__ Km,
                                                   const bf16* __restrict__ V,
                                                   bf16* __restrict__ O,
                                                   int ldq, int ldo) {
    __shared__ bf16 Qs[64][72];
    __shared__ bf16 Ks[64][72];
    __shared__ bf16 VsT[64][72];   // transposed V tile: VsT[d][m]
    __shared__ bf16 Ps[64][72];
    const int t    = threadIdx.x;
    const int wave = t >> 6, lane = t & 63;
    const int lr   = lane & 15, lkb = lane >> 4;
    const int qt   = blockIdx.x;
    const int q0   = qt * 64;
    const int b    = blockIdx.y >> 4, h = blockIdx.y & 15;
    const size_t base  = (size_t)b * LSEQ * ldq + (size_t)h * DHEAD;
    const size_t baseo = (size_t)b * LSEQ * ldo + (size_t)h * DHEAD;

#pragma unroll
    for (int p = 0; p < 2; ++p) {
        int idx = t + p * 256;
        int row = idx >> 3, c = (idx & 7) * 8;
        *reinterpret_cast<uint4*>(&Qs[row][c]) =
            *reinterpret_cast<const uint4*>(&Q[base + (size_t)(q0 + row) * ldq + c]);
    }
    __syncthreads();
    short8 qa[2];
    qa[0] = *reinterpret_cast<const short8*>(&Qs[wave * 16 + lr][lkb * 8]);
    qa[1] = *reinterpret_cast<const short8*>(&Qs[wave * 16 + lr][32 + lkb * 8]);

    f32x4 o[4];
#pragma unroll
    for (int dj = 0; dj < 4; ++dj) o[dj] = (f32x4){0.f, 0.f, 0.f, 0.f};
    float mrun[4], lrun[4];
#pragma unroll
    for (int q = 0; q < 4; ++q) { mrun[q] = -1e30f; lrun[q] = 0.f; }

    int kt0 = qt - 1; if (kt0 < 0) kt0 = 0;
    int kt1 = qt + 1; if (kt1 > LSEQ / 64 - 1) kt1 = LSEQ / 64 - 1;

    for (int kt = kt0; kt <= kt1; ++kt) {
        const int k0 = kt * 64;
        __syncthreads();
#pragma unroll
        for (int p = 0; p < 2; ++p) {
            int idx = t + p * 256;
            int row = idx >> 3, c = (idx & 7) * 8;
            *reinterpret_cast<uint4*>(&Ks[row][c]) =
                *reinterpret_cast<const uint4*>(&Km[base + (size_t)(k0 + row) * ldq + c]);
        }
        {
            const int vl = lane, vw = wave;
#pragma unroll
            for (int p = 0; p < 2; ++p) {
                int c = vw * 8 + p * 32;
                union { uint4 u; bf16 hh[8]; } tv;
                tv.u = *reinterpret_cast<const uint4*>(&V[base + (size_t)(k0 + vl) * ldq + c]);
#pragma unroll
                for (int e = 0; e < 8; ++e) VsT[c + e][vl] = tv.hh[e];
            }
        }
        __syncthreads();

        f32x4 s[4];
#pragma unroll
        for (int j = 0; j < 4; ++j) {
            short8 kb0 = *reinterpret_cast<const short8*>(&Ks[j * 16 + lr][lkb * 8]);
            short8 kb1 = *reinterpret_cast<const short8*>(&Ks[j * 16 + lr][32 + lkb * 8]);
            f32x4 z = (f32x4){0.f, 0.f, 0.f, 0.f};
            z = mfma16(qa[0], kb0, z);
            z = mfma16(qa[1], kb1, z);
            s[j] = z;
        }
        float mx[4];
#pragma unroll
        for (int q = 0; q < 4; ++q) mx[q] = -1e30f;
#pragma unroll
        for (int j = 0; j < 4; ++j) {
            int cm = k0 + j * 16 + lr;
#pragma unroll
            for (int q = 0; q < 4; ++q) {
                int rq = q0 + wave * 16 + lkb * 4 + q;
                float sv = s[j][q] * 0.125f - 0.1f * fabsf((float)(rq - cm));
                s[j][q] = sv;
                mx[q] = fmaxf(mx[q], sv);
            }
        }
#pragma unroll
        for (int q = 0; q < 4; ++q) {
#pragma unroll
            for (int off = 1; off < 16; off <<= 1)
                mx[q] = fmaxf(mx[q], __shfl_xor(mx[q], off));
        }
        float alpha[4];
#pragma unroll
        for (int q = 0; q < 4; ++q) {
            float mnew = fmaxf(mrun[q], mx[q]);
            alpha[q] = __expf(mrun[q] - mnew);
            mrun[q] = mnew;
        }
        float rs[4] = {0.f, 0.f, 0.f, 0.f};
#pragma unroll
        for (int j = 0; j < 4; ++j) {
#pragma unroll
            for (int q = 0; q < 4; ++q) {
                float p = __expf(s[j][q] - mrun[q]);
                rs[q] += p;
                Ps[wave * 16 + lkb * 4 + q][j * 16 + lr] = b16(p);
            }
        }
#pragma unroll
        for (int q = 0; q < 4; ++q) {
#pragma unroll
            for (int off = 1; off < 16; off <<= 1)
                rs[q] += __shfl_xor(rs[q], off);
            lrun[q] = lrun[q] * alpha[q] + rs[q];
        }
#pragma unroll
        for (int dj = 0; dj < 4; ++dj)
#pragma unroll
            for (int q = 0; q < 4; ++q) o[dj][q] *= alpha[q];
        // no barrier: Ps rows are wave-private

        short8 pa0 = *reinterpret_cast<const short8*>(&Ps[wave * 16 + lr][lkb * 8]);
        short8 pa1 = *reinterpret_cast<const short8*>(&Ps[wave * 16 + lr][32 + lkb * 8]);
#pragma unroll
        for (int dj = 0; dj < 4; ++dj) {
            short8 vb0 = *reinterpret_cast<const short8*>(&VsT[dj * 16 + lr][lkb * 8]);
            short8 vb1 = *reinterpret_cast<const short8*>(&VsT[dj * 16 + lr][32 + lkb * 8]);
            o[dj] = mfma16(pa0, vb0, o[dj]);
            o[dj] = mfma16(pa1, vb1, o[dj]);
        }
    }

#pragma unroll
    for (int dj = 0; dj < 4; ++dj) {
#pragma unroll
        for (int q = 0; q < 4; ++q) {
            int row = q0 + wave * 16 + lkb * 4 + q;
            int col = dj * 16 + lr;
            float val = o[dj][q] / lrun[q];
            O[baseo + (size_t)row * ldo + col] = b16(val);
        }
    }
}

// ------- moving average (k=25) + LayerNorm, 4 rows/block, XCD-chunked, bf16 in -----
__global__ __launch_bounds__(256) void mavg_ln4_kernel(const bf16* __restrict__ r,
                                                       const float* __restrict__ g,
                                                       const float* __restrict__ be,
                                                       float* __restrict__ out,
                                                       bf16* __restrict__ outb) {
    const int gid = (blockIdx.x & 7) * (MROWS / 8 / 4) + (blockIdx.x >> 3); // bijective
    const int row0 = gid * 4;
    const int b = row0 >> 11, l0 = row0 & 2047;
    const int t = threadIdx.x, c = t * 4;
    const bf16* base = r + (size_t)b * LSEQ * DMODEL;

    float4 s[4];
#pragma unroll
    for (int o = 0; o < 4; ++o) s[o] = (float4){0.f, 0.f, 0.f, 0.f};
    int j0 = l0 - 12; if (j0 < 0) j0 = 0;
    int j1 = l0 + 15; if (j1 > LSEQ - 1) j1 = LSEQ - 1;
    for (int j = j0; j <= j1; ++j) {
        union { ushort4 u; bf16 h[4]; } rv;
        rv.u = *reinterpret_cast<const ushort4*>(&base[(size_t)j * DMODEL + c]);
        float4 v; v.x = f32(rv.h[0]); v.y = f32(rv.h[1]); v.z = f32(rv.h[2]); v.w = f32(rv.h[3]);
#pragma unroll
        for (int o = 0; o < 4; ++o) {
            const int lo = l0 + o;
            if (j >= lo - 12 && j <= lo + 12) {
                s[o].x += v.x; s[o].y += v.y; s[o].z += v.z; s[o].w += v.w;
            }
        }
    }
    const float kinv = 1.0f / 25.0f;
    float4 tr[4];
    float p1[4], p2[4];
#pragma unroll
    for (int o = 0; o < 4; ++o) {
        tr[o].x = s[o].x * kinv; tr[o].y = s[o].y * kinv;
        tr[o].z = s[o].z * kinv; tr[o].w = s[o].w * kinv;
        p1[o] = tr[o].x + tr[o].y + tr[o].z + tr[o].w;
        p2[o] = tr[o].x * tr[o].x + tr[o].y * tr[o].y + tr[o].z * tr[o].z + tr[o].w * tr[o].w;
    }
    const int lane = t & 63, wv = t >> 6;
#pragma unroll
    for (int off = 1; off < 64; off <<= 1) {
#pragma unroll
        for (int o = 0; o < 4; ++o) {
            p1[o] += __shfl_xor(p1[o], off);
            p2[o] += __shfl_xor(p2[o], off);
        }
    }
    __shared__ float red[4][8];
    if (lane == 0) {
#pragma unroll
        for (int o = 0; o < 4; ++o) { red[wv][o] = p1[o]; red[wv][4 + o] = p2[o]; }
    }
    __syncthreads();
    float4 gg = *reinterpret_cast<const float4*>(&g[c]);
    float4 bb = *reinterpret_cast<const float4*>(&be[c]);
#pragma unroll
    for (int o = 0; o < 4; ++o) {
        float q1 = red[0][o] + red[1][o] + red[2][o] + red[3][o];
        float q2 = red[0][4 + o] + red[1][4 + o] + red[2][4 + o] + red[3][4 + o];
        const float mu  = q1 * (1.0f / 1024.0f);
        const float var = q2 * (1.0f / 1024.0f) - mu * mu;
        const float inv = rsqrtf(var + 1e-5f);
        float o0 = (tr[o].x - mu) * inv * gg.x + bb.x;
        float o1 = (tr[o].y - mu) * inv * gg.y + bb.y;
        float o2 = (tr[o].z - mu) * inv * gg.z + bb.z;
        float o3 = (tr[o].w - mu) * inv * gg.w + bb.w;
        if (out) {
            float4 ov; ov.x = o0; ov.y = o1; ov.z = o2; ov.w = o3;
            *reinterpret_cast<float4*>(&out[(size_t)(row0 + o) * DMODEL + c]) = ov;
        }
        if (outb) {
            union { ushort4 u; bf16 hh[4]; } ob;
            ob.hh[0] = b16(o0); ob.hh[1] = b16(o1); ob.hh[2] = b16(o2); ob.hh[3] = b16(o3);
            reinterpret_cast<ushort4*>(outb + (size_t)(row0 + o) * DMODEL)[t] = ob.u;
        }
    }
}

extern "C" void kernel_launch(void* const* d_in, const int* in_sizes, int n_in,
                              void* d_out, int out_size, void* d_ws, size_t ws_size,
                              hipStream_t stream) {
    const float* x   = (const float*)d_in[0];
    const float* Wq  = (const float*)d_in[1];
    const float* bq  = (const float*)d_in[2];
    const float* Wk  = (const float*)d_in[3];
    const float* bk  = (const float*)d_in[4];
    const float* Wv  = (const float*)d_in[5];
    const float* bv  = (const float*)d_in[6];
    const float* Wo  = (const float*)d_in[7];
    const float* bo  = (const float*)d_in[8];
    const float* W1  = (const float*)d_in[9];
    const float* b1  = (const float*)d_in[10];
    const float* W2  = (const float*)d_in[11];
    const float* b2  = (const float*)d_in[12];
    const float* g1  = (const float*)d_in[13];
    const float* be1 = (const float*)d_in[14];
    const float* g2  = (const float*)d_in[15];
    const float* be2 = (const float*)d_in[16];
    float* out = (float*)d_out;
    char* ws = (char*)d_ws;
    const size_t MB = 1u << 20;

    // timeline-overlapped layout (152MB total):
    bf16* xb    = (bf16*)(ws + 0);         //  8MB  (1-2)
    bf16* rrb   = (bf16*)(ws + 8 * MB);    //  8MB  (5-6, 9-10)
    bf16* qkvb  = (bf16*)(ws + 16 * MB);   // 24MB  (2-3)
    bf16* ab    = (bf16*)(ws + 16 * MB);   //  8MB  (6-9; qkvb dead after attn)
    bf16* hb    = (bf16*)(ws + 24 * MB);   // 32MB  (7-8)
    bf16* aob   = (bf16*)(ws + 40 * MB);   //  8MB  (3-4)
    bf16* Wqkvb = (bf16*)(ws + 48 * MB);   //  6MB  (1-2)
    bf16* Wob   = (bf16*)(ws + 54 * MB);   //  2MB  (1-4)
    bf16* W1b   = (bf16*)(ws + 56 * MB);   //  8MB  (1-7)
    bf16* W2b   = (bf16*)(ws + 64 * MB);   //  8MB  (1-8)
    bf16* P     = (bf16*)(ws + 72 * MB);   // 16MB  bf16 partials (2 slices x 8MB)
    float* bqkv = (float*)(ws + 136 * MB); // 12KB  (1-2)

    // 1. all conversions + bias concat (one dispatch, 4 y-slices)
    f2b_all<<<dim3((MROWS * DMODEL / 4) / 256, 4), 256, 0, stream>>>(
        x, W1, W2, Wq, Wk, Wv, Wo, bq, bk, bv,
        xb, W1b, W2b, Wqkvb, Wob, bqkv);

    // 2. fused QKV projection -> qkvb [4096][3072]  (16x24 = 384 blocks)
    gemmT<2><<<dim3(384, 1, 1), 512, 0, stream>>>(xb, Wqkvb, bqkv, qkvb,
                                                  MROWS, 3 * DMODEL, DMODEL, DMODEL, DMODEL, 24);
    // 3. attention (banded +-1 tile)
    attn_kernel<<<dim3(32, 32), 256, 0, stream>>>(qkvb, qkvb + DMODEL, qkvb + 2 * DMODEL,
                                                  aob, 3 * DMODEL, DMODEL);
    // 4. output projection, split-K=2 -> P[0:2] (bf16)  (16x8 x2 = 256 blocks)
    gemmT<3><<<dim3(128, 1, 2), 512, 0, stream>>>(aob, Wob, nullptr, P,
                                                  MROWS, DMODEL, DMODEL, DMODEL, DMODEL / 2, 8);
    // 5. rrb = x + sum(P0,P1) + bo  (bf16 out)
    reduce_kernel<2, false><<<(MROWS * DMODEL / 4) / 256, 256, 0, stream>>>(
        x, P, bo, rrb, MROWS * DMODEL / 4);
    // 6. movavg + LN1 -> ab (bf16 only)
    mavg_ln4_kernel<<<MROWS / 4, 256, 0, stream>>>(rrb, g1, be1, nullptr, ab);
    // 7. FF1 (GELU, bf16 out)  (16x32 = 512 blocks)
    gemmT<1><<<dim3(512, 1, 1), 512, 0, stream>>>(ab, W1b, b1, hb,
                                                  MROWS, DFF, DMODEL, DMODEL, DMODEL, 32);
    // 8. FF2, split-K=2 -> P[0:2] (bf16)  (16x8 x2 = 256 blocks, K=2048/slice)
    gemmT<3><<<dim3(128, 1, 2), 512, 0, stream>>>(hb, W2b, nullptr, P,
                                                  MROWS, DMODEL, DFF, DFF, DFF / 2, 8);
    // 9. rrb = ab + sum(P0,P1) + b2  (bf16 residual in, bf16 out)
    reduce_kernel<2, true><<<(MROWS * DMODEL / 4) / 256, 256, 0, stream>>>(
        ab, P, b2, rrb, MROWS * DMODEL / 4);
    // 10. movavg + LN2 -> out (fp32)
    mavg_ln4_kernel<<<MROWS / 4, 256, 0, stream>>>(rrb, g2, be2, out, nullptr);
}